// Round 7
// baseline (308.832 us; speedup 1.0000x reference)
//
#include <hip/hip_runtime.h>

#define BROWS 131072
#define DD 64
#define INF 128
#define NOUT 8
#define NITER 50
#define STW 76    // state column stride in u32 words (19456 B total, aliases GJ buffer)
#define GJP 65    // padded f32 stride for the in-place GJ matrix

// mats layout (floats) in ws
#define OFF_W1S   0        // [128][64]  W1s[k*64+j] = W1[j][k]
#define OFF_UWS   8192     // [64][64]   Uws[k*64+j] = Uw[j][k]
#define OFF_WSS   12288    // [64][64]   Wss[k*64+j] = W[j][k]
#define OFF_M0S   16384    // [64][64]   M0s[k*64+t] = M[t][k] = 2I - W
#define OFF_PWS   20480    // [64][16]   PwsA[j*16+o] = (o<8) ? Pw[o][j] : 0

typedef __attribute__((ext_vector_type(8))) short bf16x8;  // 4 VGPR A/B frag
typedef __attribute__((ext_vector_type(4))) float f32x4;   // 16x16 C/D frag

union FragU { uint4 u; bf16x8 f; };

// pack two f32 into one dword of 2 bf16 (bit-truncation; first arg -> low16)
__device__ __forceinline__ unsigned pk2(float a, float b) {
  return (__float_as_uint(a) >> 16) | (__float_as_uint(b) & 0xFFFF0000u);
}
// exact residual v - bf16trunc(v)
__device__ __forceinline__ float res_lo(float v) {
  return v - __uint_as_float(__float_as_uint(v) & 0xFFFF0000u);
}
__device__ __forceinline__ bf16x8 frag4(unsigned a, unsigned b, unsigned c, unsigned d) {
  FragU t; t.u.x = a; t.u.y = b; t.u.z = c; t.u.w = d; return t.f;
}
__device__ __forceinline__ f32x4 MF16(bf16x8 a, bf16x8 b, f32x4 c) {
  return __builtin_amdgcn_mfma_f32_16x16x32_bf16(a, b, c, 0, 0, 0);
}

// A-fragment (hi,lo) from streamed f32 matrix src[k*stride + j] = Mat[j][k].
// Verified map: lane holds row j, slots s=0..7 are k = kb..kb+7, kb = 32*ki+8*(lane>>4).
__device__ __forceinline__ void build_a16(const float* __restrict__ src, int stride,
    int j, int kb, float scale, bf16x8& fh, bf16x8& fl) {
  unsigned wh[4], wl[4];
  #pragma unroll
  for (int p = 0; p < 4; ++p) {
    const float v0 = src[(kb + 2*p    ) * stride + j] * scale;
    const float v1 = src[(kb + 2*p + 1) * stride + j] * scale;
    wh[p] = pk2(v0, v1);
    wl[p] = pk2(res_lo(v0), res_lo(v1));
  }
  fh = frag4(wh[0], wh[1], wh[2], wh[3]);
  fl = frag4(wl[0], wl[1], wl[2], wl[3]);
}

// R-fragment from LDS Minv (transposed, padded): Minv[j][k] = MT[k*GJP + j].
// Element (row j, slot k) = 2*Minv[j][k] - delta(j,k).
__device__ __forceinline__ void build_r16(const float* MT, int j, int kb,
                                          bf16x8& fh, bf16x8& fl) {
  unsigned wh[4], wl[4];
  #pragma unroll
  for (int p = 0; p < 4; ++p) {
    const int k0 = kb + 2*p, k1 = k0 + 1;
    const float v0 = 2.0f * MT[k0*GJP + j] - ((k0 == j) ? 1.0f : 0.0f);
    const float v1 = 2.0f * MT[k1*GJP + j] - ((k1 == j) ? 1.0f : 0.0f);
    wh[p] = pk2(v0, v1);
    wl[p] = pk2(res_lo(v0), res_lo(v1));
  }
  fh = frag4(wh[0], wh[1], wh[2], wh[3]);
  fl = frag4(wl[0], wl[1], wl[2], wl[3]);
}

// B-fragment (hi,lo) from 8 explicit f32 values, same slot map as build_a16.
__device__ __forceinline__ void build_b8(const float* v, bf16x8& fh, bf16x8& fl) {
  fh = frag4(pk2(v[0],v[1]), pk2(v[2],v[3]), pk2(v[4],v[5]), pk2(v[6],v[7]));
  fl = frag4(pk2(res_lo(v[0]),res_lo(v[1])), pk2(res_lo(v[2]),res_lo(v[3])),
             pk2(res_lo(v[4]),res_lo(v[5])), pk2(res_lo(v[6]),res_lo(v[7])));
}

// Store one C/D tile into the packed-bf16 LDS state column.
// C/D map (verified): reg r -> row 16*rt + 4*kg + r, col = lane&15.
// Column words: hi plane 0..31 (word w = rows 2w,2w+1), lo plane 32..63.
// MODE: 0 = raw, 1 = abs, 2 = relu.
template<int MODE>
__device__ __forceinline__ void store_pk(unsigned* stc, int kg, int rt, f32x4 a) {
  float x0 = a[0], x1 = a[1], x2 = a[2], x3 = a[3];
  if (MODE == 1) { x0=fabsf(x0); x1=fabsf(x1); x2=fabsf(x2); x3=fabsf(x3); }
  if (MODE == 2) { x0=fmaxf(x0,0.f); x1=fmaxf(x1,0.f); x2=fmaxf(x2,0.f); x3=fmaxf(x3,0.f); }
  uint2 h, l;
  h.x = pk2(x0, x1);                    h.y = pk2(x2, x3);
  l.x = pk2(res_lo(x0), res_lo(x1));    l.y = pk2(res_lo(x2), res_lo(x3));
  *reinterpret_cast<uint2*>(stc + 8*rt + 2*kg)      = h;
  *reinterpret_cast<uint2*>(stc + 32 + 8*rt + 2*kg) = l;
}

// acc[rt] += scale(A) @ state   (A streamed f32 64x64 in global, B = packed state)
__device__ __forceinline__ void product3(f32x4* acc, const float* __restrict__ Asrc,
    float scale, const unsigned* stc, int kg, int l15) {
  #pragma unroll
  for (int ki = 0; ki < 2; ++ki) {
    FragU bh, bl;
    bh.u = *reinterpret_cast<const uint4*>(stc + 16*ki + 4*kg);
    bl.u = *reinterpret_cast<const uint4*>(stc + 32 + 16*ki + 4*kg);
    #pragma unroll
    for (int rt = 0; rt < 4; ++rt) {
      bf16x8 ah, al;
      build_a16(Asrc, DD, 16*rt + l15, 32*ki + 8*kg, scale, ah, al);
      acc[rt] = MF16(ah, bh.f, acc[rt]);
      acc[rt] = MF16(ah, bl.f, acc[rt]);
      acc[rt] = MF16(al, bh.f, acc[rt]);
    }
  }
}

// ---------------------------------------------------------------------------
// Parallel prep: blocks 0..15 build W and M = 2I - W (f64 accumulation);
// blocks 16..67 do the streamed-layout transposes. Replaces k_layout + the
// serial half of the old k_inv.
// ---------------------------------------------------------------------------
__global__ __launch_bounds__(256) void k_prep(
    const float* __restrict__ W1, const float* __restrict__ Uw,
    const float* __restrict__ Aw, const float* __restrict__ Bw,
    const float* __restrict__ Pw, float* __restrict__ mats) {
  const int b = blockIdx.x, tid = threadIdx.x;
  if (b < 16) {
    const int k = 4*b + (tid >> 6), t = tid & 63;
    double s = 0.0;
    for (int i = 0; i < DD; ++i)
      s += (double)Aw[i*DD + t] * (double)Aw[i*DD + k];
    const double w = ((t == k) ? 0.9 : 0.0) - s
                   + (double)Bw[t*DD + k] - (double)Bw[k*DD + t];
    mats[OFF_WSS + k*DD + t] = (float)w;
    mats[OFF_M0S + k*DD + t] = (float)(((t == k) ? 2.0 : 0.0) - w);
  } else {
    const int e = (b - 16) * 256 + tid;
    if (e < 8192) {
      mats[OFF_W1S + e] = W1[(e & 63) * INF + (e >> 6)];
    } else if (e < 12288) {
      const int e2 = e - 8192;
      mats[OFF_UWS + e2] = Uw[(e2 & 63) * DD + (e2 >> 6)];
    } else if (e < 13312) {
      const int e2 = e - 12288;
      const int o = e2 & 15, j = e2 >> 4;
      mats[OFF_PWS + e2] = (o < NOUT) ? Pw[o * DD + j] : 0.0f;
    }
  }
}

// ---------------------------------------------------------------------------
// Fully fused solve. Prologue: per-block f32 in-place Gauss-Jordan of
// M = 2I - W in LDS (aliased with the state buffer), R fragments from Minv.
// Then: h = relu(W1 x + b1) [computed first, regs]; bias = Uw h + Ub;
// c2 = R bias + bias (2Winv = R + I); 49x u <- c2 + R|u|;
// zn = relu(W z + bias); out = relu(zn) Pw^T + Pb.
// ---------------------------------------------------------------------------
__global__ __launch_bounds__(256) void k_solve(
    const float* __restrict__ x,  const float* __restrict__ b1,
    const float* __restrict__ Ub, const float* __restrict__ Pb,
    const float* __restrict__ mats, float* __restrict__ out) {
  __shared__ unsigned shmem[DD * STW];   // 19456 B: GJ matrix, then packed state
  const float* W1s  = mats + OFF_W1S;
  const float* Uws  = mats + OFF_UWS;
  const float* Wss  = mats + OFF_WSS;
  const float* M0s  = mats + OFF_M0S;
  const float* PwsA = mats + OFF_PWS;
  const int tid  = threadIdx.x;
  const int lane = tid & 63, wv = tid >> 6;
  const int l15  = lane & 15, kg = lane >> 4;
  const int ccol = wv * 16 + l15;
  const size_t ncol = (size_t)blockIdx.x * 64 + ccol;
  unsigned* stc = shmem + ccol * STW;

  // ---- h = relu(W1 x^T + b1): pure global/MFMA, result held in regs over GJ
  f32x4 hC[4];
  #pragma unroll
  for (int rt = 0; rt < 4; ++rt)
    hC[rt] = *reinterpret_cast<const f32x4*>(b1 + 16*rt + 4*kg);
  #pragma unroll
  for (int ki = 0; ki < 4; ++ki) {                 // K = 128
    const float* xp = x + ncol * INF + 32*ki + 8*kg;
    float bv[8];
    #pragma unroll
    for (int s = 0; s < 8; ++s) bv[s] = xp[s];
    bf16x8 Bh, Bl; build_b8(bv, Bh, Bl);
    #pragma unroll
    for (int rt = 0; rt < 4; ++rt) {
      bf16x8 ah, al;
      build_a16(W1s, DD, 16*rt + l15, 32*ki + 8*kg, 1.0f, ah, al);
      hC[rt] = MF16(ah, Bh, hC[rt]);
      hC[rt] = MF16(ah, Bl, hC[rt]);
      hC[rt] = MF16(al, Bh, hC[rt]);
    }
  }

  // ---- stage M = 2I - W into padded transposed LDS: MT[j*GJP+t] = M[t][j]
  float* MT = reinterpret_cast<float*>(shmem);
  #pragma unroll
  for (int q = 0; q < 16; ++q) {
    const int idx = q * 256 + tid;
    MT[(idx >> 6) * GJP + (idx & 63)] = M0s[idx];
  }
  __syncthreads();

  // ---- f32 in-place Gauss-Jordan (no pivoting; sym(M) = 1.1I + A^TA is PD)
  const int tGJ = tid & 63, cgj = tid >> 6;
  #pragma unroll 1
  for (int c = 0; c < DD; ++c) {
    const float praw = MT[c*GJP + c];       // broadcast
    const float f    = MT[c*GJP + tGJ];     // lane-consecutive
    const float p    = 1.0f / praw;
    __syncthreads();
    if (tid < DD) {                         // scale pivot row of M (conflict-free: bank j+c)
      const int j = tid;
      const float v = MT[j*GJP + c];
      MT[j*GJP + c] = (j == c) ? p : v * p;
    }
    __syncthreads();
    if (tGJ != c) {                         // eliminate; row c untouched
      #pragma unroll 4
      for (int jj = 0; jj < 16; ++jj) {
        const int j = 16*cgj + jj;
        const float mc  = MT[j*GJP + c];    // broadcast (scaled pivot row)
        const float cur = MT[j*GJP + tGJ];  // lane-consecutive
        MT[j*GJP + tGJ] = fmaf(-f, mc, (j == c) ? 0.0f : cur);
      }
    }
    __syncthreads();
  }
  // MT[a*GJP+b] = Minv[b][a]

  // ---- R fragments from LDS Minv: element (j,k) = 2*Minv[j][k] - delta
  bf16x8 rFh[4][2], rFl[4][2];
  #pragma unroll
  for (int rt = 0; rt < 4; ++rt)
    #pragma unroll
    for (int ki = 0; ki < 2; ++ki)
      build_r16(MT, 16*rt + l15, 32*ki + 8*kg, rFh[rt][ki], rFl[rt][ki]);
  __syncthreads();   // MT dead -> state buffer live

  // ---- state = relu(h)
  #pragma unroll
  for (int rt = 0; rt < 4; ++rt) store_pk<2>(stc, kg, rt, hC[rt]);

  // ---- bias = Uw h + Ub (kept in regs for c2-init and zn C-init)
  f32x4 biasC[4];
  #pragma unroll
  for (int rt = 0; rt < 4; ++rt)
    biasC[rt] = *reinterpret_cast<const f32x4*>(Ub + 16*rt + 4*kg);
  product3(biasC, Uws, 1.0f, stc, kg, l15);
  #pragma unroll
  for (int rt = 0; rt < 4; ++rt) store_pk<0>(stc, kg, rt, biasC[rt]);

  // ---- c2 = 2 Winv bias = R bias + bias  (uses resident R fragments)
  f32x4 c2a[4];
  #pragma unroll
  for (int rt = 0; rt < 4; ++rt) c2a[rt] = biasC[rt];
  #pragma unroll
  for (int ki = 0; ki < 2; ++ki) {
    FragU bh, bl;
    bh.u = *reinterpret_cast<const uint4*>(stc + 16*ki + 4*kg);
    bl.u = *reinterpret_cast<const uint4*>(stc + 32 + 16*ki + 4*kg);
    #pragma unroll
    for (int rt = 0; rt < 4; ++rt) {
      c2a[rt] = MF16(rFh[rt][ki], bh.f, c2a[rt]);
      c2a[rt] = MF16(rFh[rt][ki], bl.f, c2a[rt]);
      c2a[rt] = MF16(rFl[rt][ki], bh.f, c2a[rt]);
    }
  }
  #pragma unroll
  for (int rt = 0; rt < 4; ++rt) store_pk<1>(stc, kg, rt, c2a[rt]);  // |u1| = |c2|

  // ---- u_{k+1} = c2 + R|u_k| : 48 abs iterations, then 1 relu
  f32x4 u[4];
  #pragma unroll 1
  for (int it = 0; it < NITER - 2; ++it) {
    #pragma unroll
    for (int ki = 0; ki < 2; ++ki) {
      FragU bh, bl;
      bh.u = *reinterpret_cast<const uint4*>(stc + 16*ki + 4*kg);
      bl.u = *reinterpret_cast<const uint4*>(stc + 32 + 16*ki + 4*kg);
      #pragma unroll
      for (int rt = 0; rt < 4; ++rt) {
        f32x4 base = (ki == 0) ? c2a[rt] : u[rt];
        u[rt] = MF16(rFh[rt][ki], bh.f, base);
        u[rt] = MF16(rFh[rt][ki], bl.f, u[rt]);
        u[rt] = MF16(rFl[rt][ki], bh.f, u[rt]);
      }
    }
    #pragma unroll
    for (int rt = 0; rt < 4; ++rt) store_pk<1>(stc, kg, rt, u[rt]);
  }
  // final PR step -> u50; state = z = relu(u50)
  #pragma unroll
  for (int ki = 0; ki < 2; ++ki) {
    FragU bh, bl;
    bh.u = *reinterpret_cast<const uint4*>(stc + 16*ki + 4*kg);
    bl.u = *reinterpret_cast<const uint4*>(stc + 32 + 16*ki + 4*kg);
    #pragma unroll
    for (int rt = 0; rt < 4; ++rt) {
      f32x4 base = (ki == 0) ? c2a[rt] : u[rt];
      u[rt] = MF16(rFh[rt][ki], bh.f, base);
      u[rt] = MF16(rFh[rt][ki], bl.f, u[rt]);
      u[rt] = MF16(rFl[rt][ki], bh.f, u[rt]);
    }
  }
  #pragma unroll
  for (int rt = 0; rt < 4; ++rt) store_pk<2>(stc, kg, rt, u[rt]);

  // ---- zn = relu(W z + bias), C-init = biasC (regs)
  f32x4 zn[4];
  #pragma unroll
  for (int rt = 0; rt < 4; ++rt) zn[rt] = biasC[rt];
  product3(zn, Wss, 1.0f, stc, kg, l15);
  #pragma unroll
  for (int rt = 0; rt < 4; ++rt) store_pk<2>(stc, kg, rt, zn[rt]);   // relu(zn)

  // ---- out = relu(zn) @ Pw^T + Pb via MFMA (A rows 8..15 are zero)
  f32x4 oC = (f32x4){0.f, 0.f, 0.f, 0.f};
  if (kg < 2) {
    const float4 pb = *reinterpret_cast<const float4*>(Pb + 4*kg);
    oC[0] = pb.x; oC[1] = pb.y; oC[2] = pb.z; oC[3] = pb.w;
  }
  #pragma unroll
  for (int ki = 0; ki < 2; ++ki) {
    FragU bh, bl;
    bh.u = *reinterpret_cast<const uint4*>(stc + 16*ki + 4*kg);
    bl.u = *reinterpret_cast<const uint4*>(stc + 32 + 16*ki + 4*kg);
    bf16x8 ah, al;
    build_a16(PwsA, 16, l15, 32*ki + 8*kg, 1.0f, ah, al);
    oC = MF16(ah, bh.f, oC);
    oC = MF16(ah, bl.f, oC);
    oC = MF16(al, bh.f, oC);
  }
  if (kg < 2) {
    float4* op = reinterpret_cast<float4*>(out + ncol * NOUT + 4*kg);
    *op = make_float4(oC[0], oC[1], oC[2], oC[3]);
  }
}

extern "C" void kernel_launch(void* const* d_in, const int* in_sizes, int n_in,
                              void* d_out, int out_size, void* d_ws, size_t ws_size,
                              hipStream_t stream) {
  const float* x  = (const float*)d_in[0];
  const float* W1 = (const float*)d_in[1];
  const float* b1 = (const float*)d_in[2];
  const float* Uw = (const float*)d_in[3];
  const float* Ub = (const float*)d_in[4];
  const float* Aw = (const float*)d_in[5];
  const float* Bw = (const float*)d_in[6];
  const float* Pw = (const float*)d_in[7];
  const float* Pb = (const float*)d_in[8];
  float* outp = (float*)d_out;
  float* mats = (float*)d_ws;                     // ~86 KB of streamed matrices

  k_prep  <<<68, 256, 0, stream>>>(W1, Uw, Aw, Bw, Pw, mats);
  k_solve <<<BROWS/64, 256, 0, stream>>>(x, b1, Ub, Pb, mats, outp);
}

// Round 8
// 192.364 us; speedup vs baseline: 1.6055x; 1.6055x over previous
//
#include <hip/hip_runtime.h>

#define BROWS 131072
#define DD 64
#define INF 128
#define NOUT 8
#define NITER 50
#define STW 76    // state column stride in u32 words
#define GJP 65    // padded f32 stride for the in-place GJ matrix

// mats layout (floats) in ws
#define OFF_W1S   0        // [128][64]  W1s[k*64+j] = W1[j][k]
#define OFF_UWS   8192     // [64][64]   Uws[k*64+j] = Uw[j][k]
#define OFF_WSS   12288    // [64][64]   Wss[k*64+j] = W[j][k]
#define OFF_RMS   16384    // [64][64]   Rms[k*64+j] = R[j][k] = 2*Winv[j][k] - d(j,k)
#define OFF_PWS   20480    // [64][16]   PwsA[j*16+o] = (o<8) ? Pw[o][j] : 0

typedef __attribute__((ext_vector_type(8))) short bf16x8;  // 4 VGPR A/B frag
typedef __attribute__((ext_vector_type(4))) float f32x4;   // 16x16 C/D frag

union FragU { uint4 u; bf16x8 f; };

// pack two f32 into one dword of 2 bf16 (bit-truncation; first arg -> low16)
__device__ __forceinline__ unsigned pk2(float a, float b) {
  return (__float_as_uint(a) >> 16) | (__float_as_uint(b) & 0xFFFF0000u);
}
// exact residual v - bf16trunc(v)
__device__ __forceinline__ float res_lo(float v) {
  return v - __uint_as_float(__float_as_uint(v) & 0xFFFF0000u);
}
__device__ __forceinline__ bf16x8 frag4(unsigned a, unsigned b, unsigned c, unsigned d) {
  FragU t; t.u.x = a; t.u.y = b; t.u.z = c; t.u.w = d; return t.f;
}
__device__ __forceinline__ f32x4 MF16(bf16x8 a, bf16x8 b, f32x4 c) {
  return __builtin_amdgcn_mfma_f32_16x16x32_bf16(a, b, c, 0, 0, 0);
}

// A-fragment (hi,lo) from streamed f32 matrix src[k*stride + j] = Mat[j][k].
// Verified map: lane holds row j, slots s=0..7 are k = kb..kb+7, kb = 32*ki+8*(lane>>4).
__device__ __forceinline__ void build_a16(const float* __restrict__ src, int stride,
    int j, int kb, float scale, bf16x8& fh, bf16x8& fl) {
  unsigned wh[4], wl[4];
  #pragma unroll
  for (int p = 0; p < 4; ++p) {
    const float v0 = src[(kb + 2*p    ) * stride + j] * scale;
    const float v1 = src[(kb + 2*p + 1) * stride + j] * scale;
    wh[p] = pk2(v0, v1);
    wl[p] = pk2(res_lo(v0), res_lo(v1));
  }
  fh = frag4(wh[0], wh[1], wh[2], wh[3]);
  fl = frag4(wl[0], wl[1], wl[2], wl[3]);
}

// B-fragment (hi,lo) from 8 explicit f32 values, same slot map as build_a16.
__device__ __forceinline__ void build_b8(const float* v, bf16x8& fh, bf16x8& fl) {
  fh = frag4(pk2(v[0],v[1]), pk2(v[2],v[3]), pk2(v[4],v[5]), pk2(v[6],v[7]));
  fl = frag4(pk2(res_lo(v[0]),res_lo(v[1])), pk2(res_lo(v[2]),res_lo(v[3])),
             pk2(res_lo(v[4]),res_lo(v[5])), pk2(res_lo(v[6]),res_lo(v[7])));
}

// Store one C/D tile into the packed-bf16 LDS state column.
// C/D map (verified): reg r -> row 16*rt + 4*kg + r, col = lane&15.
// Column words: hi plane 0..31 (word w = rows 2w,2w+1), lo plane 32..63.
// MODE: 0 = raw, 1 = abs, 2 = relu.
template<int MODE>
__device__ __forceinline__ void store_pk(unsigned* stc, int kg, int rt, f32x4 a) {
  float x0 = a[0], x1 = a[1], x2 = a[2], x3 = a[3];
  if (MODE == 1) { x0=fabsf(x0); x1=fabsf(x1); x2=fabsf(x2); x3=fabsf(x3); }
  if (MODE == 2) { x0=fmaxf(x0,0.f); x1=fmaxf(x1,0.f); x2=fmaxf(x2,0.f); x3=fmaxf(x3,0.f); }
  uint2 h, l;
  h.x = pk2(x0, x1);                    h.y = pk2(x2, x3);
  l.x = pk2(res_lo(x0), res_lo(x1));    l.y = pk2(res_lo(x2), res_lo(x3));
  *reinterpret_cast<uint2*>(stc + 8*rt + 2*kg)      = h;
  *reinterpret_cast<uint2*>(stc + 32 + 8*rt + 2*kg) = l;
}

// acc[rt] += scale(A) @ state   (A streamed f32 64x64 in global, B = packed state)
__device__ __forceinline__ void product3(f32x4* acc, const float* __restrict__ Asrc,
    float scale, const unsigned* stc, int kg, int l15) {
  #pragma unroll
  for (int ki = 0; ki < 2; ++ki) {
    FragU bh, bl;
    bh.u = *reinterpret_cast<const uint4*>(stc + 16*ki + 4*kg);
    bl.u = *reinterpret_cast<const uint4*>(stc + 32 + 16*ki + 4*kg);
    #pragma unroll
    for (int rt = 0; rt < 4; ++rt) {
      bf16x8 ah, al;
      build_a16(Asrc, DD, 16*rt + l15, 32*ki + 8*kg, scale, ah, al);
      acc[rt] = MF16(ah, bh.f, acc[rt]);
      acc[rt] = MF16(ah, bl.f, acc[rt]);
      acc[rt] = MF16(al, bh.f, acc[rt]);
    }
  }
}

// ---------------------------------------------------------------------------
// One prep kernel, 35 blocks x 512:
//   blocks 0..7  : W = 0.9I - A^T A + Bw - Bw^T  ->  Wss (f64 dots, parallel)
//   blocks 8..33 : streamed transposes W1s / Uws / PwsA
//   block  34    : stage Aw in LDS, f32 A^T A, M = 2I - W (padded transposed),
//                  f32 in-place no-pivot Gauss-Jordan (round-7-verified),
//                  emit Rms = 2*Minv - I streamed.
// Wall time = block 34 (~15-20 us); everything else finishes earlier.
// ---------------------------------------------------------------------------
__global__ __launch_bounds__(512) void k_prep(
    const float* __restrict__ W1, const float* __restrict__ Uw,
    const float* __restrict__ Aw, const float* __restrict__ Bw,
    const float* __restrict__ Pw, float* __restrict__ mats) {
  const int b = blockIdx.x, tid = threadIdx.x;

  if (b < 8) {            // ---- Wss (each thread one element)
    const int e = b * 512 + tid;
    const int t = e & 63, k = e >> 6;
    double s = 0.0;
    for (int i = 0; i < DD; ++i)
      s += (double)Aw[i*DD + t] * (double)Aw[i*DD + k];
    const double w = ((t == k) ? 0.9 : 0.0) - s
                   + (double)Bw[t*DD + k] - (double)Bw[k*DD + t];
    mats[OFF_WSS + k*DD + t] = (float)w;
    return;
  }
  if (b < 34) {           // ---- transposes
    const int e = (b - 8) * 512 + tid;
    if (e < 8192) {
      mats[OFF_W1S + e] = W1[(e & 63) * INF + (e >> 6)];
    } else if (e < 12288) {
      const int e2 = e - 8192;
      mats[OFF_UWS + e2] = Uw[(e2 & 63) * DD + (e2 >> 6)];
    } else if (e < 13312) {
      const int e2 = e - 12288;
      const int o = e2 & 15, j = e2 >> 4;
      mats[OFF_PWS + e2] = (o < NOUT) ? Pw[o * DD + j] : 0.0f;
    }
    return;
  }

  // ---- block 34: the inversion block
  __shared__ float As[DD * DD];      // 16 KB Aw staging
  __shared__ float MT[DD * GJP];     // 16.6 KB padded: MT[j*GJP+t] = M[t][j]
  const int t = tid & 63;            // owned column of MT rows (= row of M)
  const int cg = tid >> 6;           // 0..7

  #pragma unroll
  for (int q = 0; q < 8; ++q) As[q * 512 + tid] = Aw[q * 512 + tid];
  __syncthreads();

  // S[t][k] for k = 8*cg..8*cg+7; M[t][k] = 2d - W[t][k]; store at MT[k*GJP+t]
  {
    float s[8];
    #pragma unroll
    for (int q = 0; q < 8; ++q) s[q] = 0.0f;
    for (int i = 0; i < DD; ++i) {
      const float at = As[i*DD + t];            // lane-consecutive
      const float* ak = As + i*DD + 8*cg;       // broadcast per 64-group
      #pragma unroll
      for (int q = 0; q < 8; ++q) s[q] = fmaf(at, ak[q], s[q]);
    }
    #pragma unroll
    for (int q = 0; q < 8; ++q) {
      const int k = 8*cg + q;
      const float w = ((t == k) ? 0.9f : 0.0f) - s[q] + Bw[t*DD + k] - Bw[k*DD + t];
      MT[k*GJP + t] = ((t == k) ? 2.0f : 0.0f) - w;
    }
  }
  __syncthreads();

  // f32 in-place no-pivot Gauss-Jordan (verified round 7), 512 threads
  #pragma unroll 1
  for (int c = 0; c < DD; ++c) {
    const float praw = MT[c*GJP + c];       // broadcast
    const float f    = MT[c*GJP + t];       // lane-consecutive
    const float p    = 1.0f / praw;
    __syncthreads();
    if (tid < DD) {                         // scale pivot row of M
      const int j = tid;
      const float v = MT[j*GJP + c];
      MT[j*GJP + c] = (j == c) ? p : v * p;
    }
    __syncthreads();
    if (t != c) {                           // eliminate; row c untouched
      #pragma unroll
      for (int jj = 0; jj < 8; ++jj) {
        const int j = 8*cg + jj;
        const float mc  = MT[j*GJP + c];    // broadcast (scaled pivot row)
        const float cur = MT[j*GJP + t];    // lane-consecutive
        MT[j*GJP + t] = fmaf(-f, mc, (j == c) ? 0.0f : cur);
      }
    }
    __syncthreads();
  }
  // MT[a*GJP+b] = Minv[b][a]

  // emit Rms[k*DD + j] = 2*Minv[j][k] - d(j,k)   (Minv[j][k] = MT[k*GJP+j])
  #pragma unroll
  for (int q = 0; q < 8; ++q) {
    const int k = 8*cg + q;
    const float wi = MT[k*GJP + t];
    mats[OFF_RMS + k*DD + t] = 2.0f * wi - ((k == t) ? 1.0f : 0.0f);
  }
}

// ---------------------------------------------------------------------------
// Fused solve (round-6 body, 180 us measured; + round-7's exact fold
// c2 = R bias + bias so no Winv fragments are needed).
// Per wave: 64 dims x 16 batch cols, barrier-free.
// ---------------------------------------------------------------------------
__global__ __launch_bounds__(256) void k_solve(
    const float* __restrict__ x,  const float* __restrict__ b1,
    const float* __restrict__ Ub, const float* __restrict__ Pb,
    const float* __restrict__ mats, float* __restrict__ out) {
  __shared__ unsigned stp[DD * STW];   // packed state, one 76-word column per batch col
  const float* W1s  = mats + OFF_W1S;
  const float* Uws  = mats + OFF_UWS;
  const float* Wss  = mats + OFF_WSS;
  const float* Rms  = mats + OFF_RMS;
  const float* PwsA = mats + OFF_PWS;
  const int tid  = threadIdx.x;
  const int lane = tid & 63, wv = tid >> 6;
  const int l15  = lane & 15, kg = lane >> 4;
  const int ccol = wv * 16 + l15;
  const size_t ncol = (size_t)blockIdx.x * 64 + ccol;
  unsigned* stc = stp + ccol * STW;

  // R fragments resident in registers for all iterations
  bf16x8 rFh[4][2], rFl[4][2];
  #pragma unroll
  for (int rt = 0; rt < 4; ++rt)
    #pragma unroll
    for (int ki = 0; ki < 2; ++ki)
      build_a16(Rms, DD, 16*rt + l15, 32*ki + 8*kg, 1.0f, rFh[rt][ki], rFl[rt][ki]);

  // ---- h = relu(W1 x^T + b1): B from x directly (same slot map -> pi-cancel)
  f32x4 hC[4];
  #pragma unroll
  for (int rt = 0; rt < 4; ++rt)
    hC[rt] = *reinterpret_cast<const f32x4*>(b1 + 16*rt + 4*kg);
  #pragma unroll
  for (int ki = 0; ki < 4; ++ki) {                 // K = 128
    const float* xp = x + ncol * INF + 32*ki + 8*kg;
    float bv[8];
    #pragma unroll
    for (int s = 0; s < 8; ++s) bv[s] = xp[s];
    bf16x8 Bh, Bl; build_b8(bv, Bh, Bl);
    #pragma unroll
    for (int rt = 0; rt < 4; ++rt) {
      bf16x8 ah, al;
      build_a16(W1s, DD, 16*rt + l15, 32*ki + 8*kg, 1.0f, ah, al);
      hC[rt] = MF16(ah, Bh, hC[rt]);
      hC[rt] = MF16(ah, Bl, hC[rt]);
      hC[rt] = MF16(al, Bh, hC[rt]);
    }
  }
  #pragma unroll
  for (int rt = 0; rt < 4; ++rt) store_pk<2>(stc, kg, rt, hC[rt]);   // relu(h)

  // ---- bias = Uw h + Ub (kept in regs for c2-init and zn C-init)
  f32x4 biasC[4];
  #pragma unroll
  for (int rt = 0; rt < 4; ++rt)
    biasC[rt] = *reinterpret_cast<const f32x4*>(Ub + 16*rt + 4*kg);
  product3(biasC, Uws, 1.0f, stc, kg, l15);
  #pragma unroll
  for (int rt = 0; rt < 4; ++rt) store_pk<0>(stc, kg, rt, biasC[rt]);

  // ---- c2 = 2 Winv bias = R bias + bias  (uses resident R fragments)
  f32x4 c2a[4];
  #pragma unroll
  for (int rt = 0; rt < 4; ++rt) c2a[rt] = biasC[rt];
  #pragma unroll
  for (int ki = 0; ki < 2; ++ki) {
    FragU bh, bl;
    bh.u = *reinterpret_cast<const uint4*>(stc + 16*ki + 4*kg);
    bl.u = *reinterpret_cast<const uint4*>(stc + 32 + 16*ki + 4*kg);
    #pragma unroll
    for (int rt = 0; rt < 4; ++rt) {
      c2a[rt] = MF16(rFh[rt][ki], bh.f, c2a[rt]);
      c2a[rt] = MF16(rFh[rt][ki], bl.f, c2a[rt]);
      c2a[rt] = MF16(rFl[rt][ki], bh.f, c2a[rt]);
    }
  }
  #pragma unroll
  for (int rt = 0; rt < 4; ++rt) store_pk<1>(stc, kg, rt, c2a[rt]);  // |u1| = |c2|

  // ---- u_{k+1} = c2 + R|u_k| : 48 abs iterations, then 1 relu
  f32x4 u[4];
  #pragma unroll 1
  for (int it = 0; it < NITER - 2; ++it) {
    #pragma unroll
    for (int ki = 0; ki < 2; ++ki) {
      FragU bh, bl;
      bh.u = *reinterpret_cast<const uint4*>(stc + 16*ki + 4*kg);
      bl.u = *reinterpret_cast<const uint4*>(stc + 32 + 16*ki + 4*kg);
      #pragma unroll
      for (int rt = 0; rt < 4; ++rt) {
        f32x4 base = (ki == 0) ? c2a[rt] : u[rt];
        u[rt] = MF16(rFh[rt][ki], bh.f, base);
        u[rt] = MF16(rFh[rt][ki], bl.f, u[rt]);
        u[rt] = MF16(rFl[rt][ki], bh.f, u[rt]);
      }
    }
    #pragma unroll
    for (int rt = 0; rt < 4; ++rt) store_pk<1>(stc, kg, rt, u[rt]);
  }
  // final PR step -> u50; state = z = relu(u50)
  #pragma unroll
  for (int ki = 0; ki < 2; ++ki) {
    FragU bh, bl;
    bh.u = *reinterpret_cast<const uint4*>(stc + 16*ki + 4*kg);
    bl.u = *reinterpret_cast<const uint4*>(stc + 32 + 16*ki + 4*kg);
    #pragma unroll
    for (int rt = 0; rt < 4; ++rt) {
      f32x4 base = (ki == 0) ? c2a[rt] : u[rt];
      u[rt] = MF16(rFh[rt][ki], bh.f, base);
      u[rt] = MF16(rFh[rt][ki], bl.f, u[rt]);
      u[rt] = MF16(rFl[rt][ki], bh.f, u[rt]);
    }
  }
  #pragma unroll
  for (int rt = 0; rt < 4; ++rt) store_pk<2>(stc, kg, rt, u[rt]);

  // ---- zn = relu(W z + bias), C-init = biasC (regs)
  f32x4 zn[4];
  #pragma unroll
  for (int rt = 0; rt < 4; ++rt) zn[rt] = biasC[rt];
  product3(zn, Wss, 1.0f, stc, kg, l15);
  #pragma unroll
  for (int rt = 0; rt < 4; ++rt) store_pk<2>(stc, kg, rt, zn[rt]);   // relu(zn)

  // ---- out = relu(zn) @ Pw^T + Pb via MFMA (A rows 8..15 are zero)
  f32x4 oC = (f32x4){0.f, 0.f, 0.f, 0.f};
  if (kg < 2) {
    const float4 pb = *reinterpret_cast<const float4*>(Pb + 4*kg);
    oC[0] = pb.x; oC[1] = pb.y; oC[2] = pb.z; oC[3] = pb.w;
  }
  #pragma unroll
  for (int ki = 0; ki < 2; ++ki) {
    FragU bh, bl;
    bh.u = *reinterpret_cast<const uint4*>(stc + 16*ki + 4*kg);
    bl.u = *reinterpret_cast<const uint4*>(stc + 32 + 16*ki + 4*kg);
    bf16x8 ah, al;
    build_a16(PwsA, 16, l15, 32*ki + 8*kg, 1.0f, ah, al);
    oC = MF16(ah, bh.f, oC);
    oC = MF16(ah, bl.f, oC);
    oC = MF16(al, bh.f, oC);
  }
  if (kg < 2) {
    float4* op = reinterpret_cast<float4*>(out + ncol * NOUT + 4*kg);
    *op = make_float4(oC[0], oC[1], oC[2], oC[3]);
  }
}

extern "C" void kernel_launch(void* const* d_in, const int* in_sizes, int n_in,
                              void* d_out, int out_size, void* d_ws, size_t ws_size,
                              hipStream_t stream) {
  const float* x  = (const float*)d_in[0];
  const float* W1 = (const float*)d_in[1];
  const float* b1 = (const float*)d_in[2];
  const float* Uw = (const float*)d_in[3];
  const float* Ub = (const float*)d_in[4];
  const float* Aw = (const float*)d_in[5];
  const float* Bw = (const float*)d_in[6];
  const float* Pw = (const float*)d_in[7];
  const float* Pb = (const float*)d_in[8];
  float* outp = (float*)d_out;
  float* mats = (float*)d_ws;                     // ~86 KB of streamed matrices

  k_prep  <<<35, 512, 0, stream>>>(W1, Uw, Aw, Bw, Pw, mats);
  k_solve <<<BROWS/64, 256, 0, stream>>>(x, b1, Ub, Pb, mats, outp);
}

// Round 9
// 154.032 us; speedup vs baseline: 2.0050x; 1.2489x over previous
//
#include <hip/hip_runtime.h>

#define BROWS 131072
#define DD 64
#define INF 128
#define NOUT 8
#define NITER 50
#define STW 76    // state column stride in u32 words
#define GJP 65    // padded f32 stride for the in-place GJ matrix
#define NCHEAP 38 // hi-plane-only iterations (u2..u39)
#define NFULL 9   // full two-plane iterations after the bridge (u41..u49)

// mats layout (floats) in ws
#define OFF_W1S   0        // [128][64]  W1s[k*64+j] = W1[j][k]
#define OFF_UWS   8192     // [64][64]   Uws[k*64+j] = Uw[j][k]
#define OFF_WSS   12288    // [64][64]   Wss[k*64+j] = W[j][k]
#define OFF_RMS   16384    // [64][64]   Rms[k*64+j] = R[j][k] = 2*Winv[j][k] - d(j,k)
#define OFF_PWS   20480    // [64][16]   PwsA[j*16+o] = (o<8) ? Pw[o][j] : 0

typedef __attribute__((ext_vector_type(8))) short bf16x8;  // 4 VGPR A/B frag
typedef __attribute__((ext_vector_type(4))) float f32x4;   // 16x16 C/D frag

union FragU { uint4 u; bf16x8 f; };

// pack two f32 into one dword of 2 bf16 (bit-truncation; first arg -> low16)
__device__ __forceinline__ unsigned pk2(float a, float b) {
  return (__float_as_uint(a) >> 16) | (__float_as_uint(b) & 0xFFFF0000u);
}
// exact residual v - bf16trunc(v)
__device__ __forceinline__ float res_lo(float v) {
  return v - __uint_as_float(__float_as_uint(v) & 0xFFFF0000u);
}
__device__ __forceinline__ bf16x8 frag4(unsigned a, unsigned b, unsigned c, unsigned d) {
  FragU t; t.u.x = a; t.u.y = b; t.u.z = c; t.u.w = d; return t.f;
}
__device__ __forceinline__ f32x4 MF16(bf16x8 a, bf16x8 b, f32x4 c) {
  return __builtin_amdgcn_mfma_f32_16x16x32_bf16(a, b, c, 0, 0, 0);
}

// A-fragment (hi,lo) from streamed f32 matrix src[k*stride + j] = Mat[j][k].
// Verified map: lane holds row j, slots s=0..7 are k = kb..kb+7, kb = 32*ki+8*(lane>>4).
__device__ __forceinline__ void build_a16(const float* __restrict__ src, int stride,
    int j, int kb, float scale, bf16x8& fh, bf16x8& fl) {
  unsigned wh[4], wl[4];
  #pragma unroll
  for (int p = 0; p < 4; ++p) {
    const float v0 = src[(kb + 2*p    ) * stride + j] * scale;
    const float v1 = src[(kb + 2*p + 1) * stride + j] * scale;
    wh[p] = pk2(v0, v1);
    wl[p] = pk2(res_lo(v0), res_lo(v1));
  }
  fh = frag4(wh[0], wh[1], wh[2], wh[3]);
  fl = frag4(wl[0], wl[1], wl[2], wl[3]);
}

// B-fragment (hi,lo) from 8 explicit f32 values, same slot map as build_a16.
__device__ __forceinline__ void build_b8(const float* v, bf16x8& fh, bf16x8& fl) {
  fh = frag4(pk2(v[0],v[1]), pk2(v[2],v[3]), pk2(v[4],v[5]), pk2(v[6],v[7]));
  fl = frag4(pk2(res_lo(v[0]),res_lo(v[1])), pk2(res_lo(v[2]),res_lo(v[3])),
             pk2(res_lo(v[4]),res_lo(v[5])), pk2(res_lo(v[6]),res_lo(v[7])));
}

// Store one C/D tile into the packed-bf16 LDS state column (both planes).
// C/D map (verified): reg r -> row 16*rt + 4*kg + r, col = lane&15.
// Column words: hi plane 0..31 (word w = rows 2w,2w+1), lo plane 32..63.
// MODE: 0 = raw, 1 = abs, 2 = relu.
template<int MODE>
__device__ __forceinline__ void store_pk(unsigned* stc, int kg, int rt, f32x4 a) {
  float x0 = a[0], x1 = a[1], x2 = a[2], x3 = a[3];
  if (MODE == 1) { x0=fabsf(x0); x1=fabsf(x1); x2=fabsf(x2); x3=fabsf(x3); }
  if (MODE == 2) { x0=fmaxf(x0,0.f); x1=fmaxf(x1,0.f); x2=fmaxf(x2,0.f); x3=fmaxf(x3,0.f); }
  uint2 h, l;
  h.x = pk2(x0, x1);                    h.y = pk2(x2, x3);
  l.x = pk2(res_lo(x0), res_lo(x1));    l.y = pk2(res_lo(x2), res_lo(x3));
  *reinterpret_cast<uint2*>(stc + 8*rt + 2*kg)      = h;
  *reinterpret_cast<uint2*>(stc + 32 + 8*rt + 2*kg) = l;
}

// Hi-plane-only store (cheap iterations): no residual, half the LDS traffic.
template<int MODE>
__device__ __forceinline__ void store_hi(unsigned* stc, int kg, int rt, f32x4 a) {
  float x0 = a[0], x1 = a[1], x2 = a[2], x3 = a[3];
  if (MODE == 1) { x0=fabsf(x0); x1=fabsf(x1); x2=fabsf(x2); x3=fabsf(x3); }
  uint2 h;
  h.x = pk2(x0, x1);                    h.y = pk2(x2, x3);
  *reinterpret_cast<uint2*>(stc + 8*rt + 2*kg) = h;
}

// acc[rt] += scale(A) @ state   (A streamed f32 64x64 in global, B = packed state)
__device__ __forceinline__ void product3(f32x4* acc, const float* __restrict__ Asrc,
    float scale, const unsigned* stc, int kg, int l15) {
  #pragma unroll
  for (int ki = 0; ki < 2; ++ki) {
    FragU bh, bl;
    bh.u = *reinterpret_cast<const uint4*>(stc + 16*ki + 4*kg);
    bl.u = *reinterpret_cast<const uint4*>(stc + 32 + 16*ki + 4*kg);
    #pragma unroll
    for (int rt = 0; rt < 4; ++rt) {
      bf16x8 ah, al;
      build_a16(Asrc, DD, 16*rt + l15, 32*ki + 8*kg, scale, ah, al);
      acc[rt] = MF16(ah, bh.f, acc[rt]);
      acc[rt] = MF16(ah, bl.f, acc[rt]);
      acc[rt] = MF16(al, bh.f, acc[rt]);
    }
  }
}

// ---------------------------------------------------------------------------
// One prep kernel, 35 blocks x 512 (unchanged, measured good):
//   blocks 0..7: Wss; blocks 8..33: transposes; block 34: f32 GJ -> Rms.
// ---------------------------------------------------------------------------
__global__ __launch_bounds__(512) void k_prep(
    const float* __restrict__ W1, const float* __restrict__ Uw,
    const float* __restrict__ Aw, const float* __restrict__ Bw,
    const float* __restrict__ Pw, float* __restrict__ mats) {
  const int b = blockIdx.x, tid = threadIdx.x;

  if (b < 8) {            // ---- Wss (each thread one element)
    const int e = b * 512 + tid;
    const int t = e & 63, k = e >> 6;
    double s = 0.0;
    for (int i = 0; i < DD; ++i)
      s += (double)Aw[i*DD + t] * (double)Aw[i*DD + k];
    const double w = ((t == k) ? 0.9 : 0.0) - s
                   + (double)Bw[t*DD + k] - (double)Bw[k*DD + t];
    mats[OFF_WSS + k*DD + t] = (float)w;
    return;
  }
  if (b < 34) {           // ---- transposes
    const int e = (b - 8) * 512 + tid;
    if (e < 8192) {
      mats[OFF_W1S + e] = W1[(e & 63) * INF + (e >> 6)];
    } else if (e < 12288) {
      const int e2 = e - 8192;
      mats[OFF_UWS + e2] = Uw[(e2 & 63) * DD + (e2 >> 6)];
    } else if (e < 13312) {
      const int e2 = e - 12288;
      const int o = e2 & 15, j = e2 >> 4;
      mats[OFF_PWS + e2] = (o < NOUT) ? Pw[o * DD + j] : 0.0f;
    }
    return;
  }

  // ---- block 34: the inversion block
  __shared__ float As[DD * DD];      // 16 KB Aw staging
  __shared__ float MT[DD * GJP];     // 16.6 KB padded: MT[j*GJP+t] = M[t][j]
  const int t = tid & 63;
  const int cg = tid >> 6;           // 0..7

  #pragma unroll
  for (int q = 0; q < 8; ++q) As[q * 512 + tid] = Aw[q * 512 + tid];
  __syncthreads();

  {
    float s[8];
    #pragma unroll
    for (int q = 0; q < 8; ++q) s[q] = 0.0f;
    for (int i = 0; i < DD; ++i) {
      const float at = As[i*DD + t];
      const float* ak = As + i*DD + 8*cg;
      #pragma unroll
      for (int q = 0; q < 8; ++q) s[q] = fmaf(at, ak[q], s[q]);
    }
    #pragma unroll
    for (int q = 0; q < 8; ++q) {
      const int k = 8*cg + q;
      const float w = ((t == k) ? 0.9f : 0.0f) - s[q] + Bw[t*DD + k] - Bw[k*DD + t];
      MT[k*GJP + t] = ((t == k) ? 2.0f : 0.0f) - w;
    }
  }
  __syncthreads();

  #pragma unroll 1
  for (int c = 0; c < DD; ++c) {
    const float praw = MT[c*GJP + c];
    const float f    = MT[c*GJP + t];
    const float p    = 1.0f / praw;
    __syncthreads();
    if (tid < DD) {
      const int j = tid;
      const float v = MT[j*GJP + c];
      MT[j*GJP + c] = (j == c) ? p : v * p;
    }
    __syncthreads();
    if (t != c) {
      #pragma unroll
      for (int jj = 0; jj < 8; ++jj) {
        const int j = 8*cg + jj;
        const float mc  = MT[j*GJP + c];
        const float cur = MT[j*GJP + t];
        MT[j*GJP + t] = fmaf(-f, mc, (j == c) ? 0.0f : cur);
      }
    }
    __syncthreads();
  }

  #pragma unroll
  for (int q = 0; q < 8; ++q) {
    const int k = 8*cg + q;
    const float wi = MT[k*GJP + t];
    mats[OFF_RMS + k*DD + t] = 2.0f * wi - ((k == t) ? 1.0f : 0.0f);
  }
}

// ---------------------------------------------------------------------------
// Fused solve. Iterations u2..u39 run single-plane (hi-bf16 state, 2-term,
// 16 MFMA); bridge + 9 full two-plane iterations + final step polish the
// fixed point (rho^10 decay of the cheap-phase error).
// ---------------------------------------------------------------------------
__global__ __launch_bounds__(256) void k_solve(
    const float* __restrict__ x,  const float* __restrict__ b1,
    const float* __restrict__ Ub, const float* __restrict__ Pb,
    const float* __restrict__ mats, float* __restrict__ out) {
  __shared__ unsigned stp[DD * STW];   // packed state, one 76-word column per batch col
  const float* W1s  = mats + OFF_W1S;
  const float* Uws  = mats + OFF_UWS;
  const float* Wss  = mats + OFF_WSS;
  const float* Rms  = mats + OFF_RMS;
  const float* PwsA = mats + OFF_PWS;
  const int tid  = threadIdx.x;
  const int lane = tid & 63, wv = tid >> 6;
  const int l15  = lane & 15, kg = lane >> 4;
  const int ccol = wv * 16 + l15;
  const size_t ncol = (size_t)blockIdx.x * 64 + ccol;
  unsigned* stc = stp + ccol * STW;

  // R fragments resident in registers for all iterations
  bf16x8 rFh[4][2], rFl[4][2];
  #pragma unroll
  for (int rt = 0; rt < 4; ++rt)
    #pragma unroll
    for (int ki = 0; ki < 2; ++ki)
      build_a16(Rms, DD, 16*rt + l15, 32*ki + 8*kg, 1.0f, rFh[rt][ki], rFl[rt][ki]);

  // ---- h = relu(W1 x^T + b1)
  f32x4 hC[4];
  #pragma unroll
  for (int rt = 0; rt < 4; ++rt)
    hC[rt] = *reinterpret_cast<const f32x4*>(b1 + 16*rt + 4*kg);
  #pragma unroll
  for (int ki = 0; ki < 4; ++ki) {                 // K = 128
    const float* xp = x + ncol * INF + 32*ki + 8*kg;
    float bv[8];
    #pragma unroll
    for (int s = 0; s < 8; ++s) bv[s] = xp[s];
    bf16x8 Bh, Bl; build_b8(bv, Bh, Bl);
    #pragma unroll
    for (int rt = 0; rt < 4; ++rt) {
      bf16x8 ah, al;
      build_a16(W1s, DD, 16*rt + l15, 32*ki + 8*kg, 1.0f, ah, al);
      hC[rt] = MF16(ah, Bh, hC[rt]);
      hC[rt] = MF16(ah, Bl, hC[rt]);
      hC[rt] = MF16(al, Bh, hC[rt]);
    }
  }
  #pragma unroll
  for (int rt = 0; rt < 4; ++rt) store_pk<2>(stc, kg, rt, hC[rt]);   // relu(h), full

  // ---- bias = Uw h + Ub (kept in regs for c2-init and zn C-init)
  f32x4 biasC[4];
  #pragma unroll
  for (int rt = 0; rt < 4; ++rt)
    biasC[rt] = *reinterpret_cast<const f32x4*>(Ub + 16*rt + 4*kg);
  product3(biasC, Uws, 1.0f, stc, kg, l15);
  #pragma unroll
  for (int rt = 0; rt < 4; ++rt) store_pk<0>(stc, kg, rt, biasC[rt]);

  // ---- c2 = 2 Winv bias = R bias + bias  (resident R fragments)
  f32x4 c2a[4];
  #pragma unroll
  for (int rt = 0; rt < 4; ++rt) c2a[rt] = biasC[rt];
  #pragma unroll
  for (int ki = 0; ki < 2; ++ki) {
    FragU bh, bl;
    bh.u = *reinterpret_cast<const uint4*>(stc + 16*ki + 4*kg);
    bl.u = *reinterpret_cast<const uint4*>(stc + 32 + 16*ki + 4*kg);
    #pragma unroll
    for (int rt = 0; rt < 4; ++rt) {
      c2a[rt] = MF16(rFh[rt][ki], bh.f, c2a[rt]);
      c2a[rt] = MF16(rFh[rt][ki], bl.f, c2a[rt]);
      c2a[rt] = MF16(rFl[rt][ki], bh.f, c2a[rt]);
    }
  }
  // |u1| = |c2|, hi-only (lo decays by rho^49)
  #pragma unroll
  for (int rt = 0; rt < 4; ++rt) store_hi<1>(stc, kg, rt, c2a[rt]);

  f32x4 u[4];
  // ---- cheap phase: 38 iterations, 2-term (Rh+Rl)(s_hi), hi-only store -> u2..u39
  #pragma unroll 1
  for (int it = 0; it < NCHEAP; ++it) {
    #pragma unroll
    for (int ki = 0; ki < 2; ++ki) {
      FragU bh;
      bh.u = *reinterpret_cast<const uint4*>(stc + 16*ki + 4*kg);
      #pragma unroll
      for (int rt = 0; rt < 4; ++rt) {
        f32x4 base = (ki == 0) ? c2a[rt] : u[rt];
        u[rt] = MF16(rFh[rt][ki], bh.f, base);
        u[rt] = MF16(rFl[rt][ki], bh.f, u[rt]);
      }
    }
    #pragma unroll
    for (int rt = 0; rt < 4; ++rt) store_hi<1>(stc, kg, rt, u[rt]);
  }

  // ---- bridge: 2-term read (state has hi only), FULL store -> u40
  #pragma unroll
  for (int ki = 0; ki < 2; ++ki) {
    FragU bh;
    bh.u = *reinterpret_cast<const uint4*>(stc + 16*ki + 4*kg);
    #pragma unroll
    for (int rt = 0; rt < 4; ++rt) {
      f32x4 base = (ki == 0) ? c2a[rt] : u[rt];
      u[rt] = MF16(rFh[rt][ki], bh.f, base);
      u[rt] = MF16(rFl[rt][ki], bh.f, u[rt]);
    }
  }
  #pragma unroll
  for (int rt = 0; rt < 4; ++rt) store_pk<1>(stc, kg, rt, u[rt]);

  // ---- full phase: 9 iterations, 3-term, full store -> u41..u49
  #pragma unroll 1
  for (int it = 0; it < NFULL; ++it) {
    #pragma unroll
    for (int ki = 0; ki < 2; ++ki) {
      FragU bh, bl;
      bh.u = *reinterpret_cast<const uint4*>(stc + 16*ki + 4*kg);
      bl.u = *reinterpret_cast<const uint4*>(stc + 32 + 16*ki + 4*kg);
      #pragma unroll
      for (int rt = 0; rt < 4; ++rt) {
        f32x4 base = (ki == 0) ? c2a[rt] : u[rt];
        u[rt] = MF16(rFh[rt][ki], bh.f, base);
        u[rt] = MF16(rFh[rt][ki], bl.f, u[rt]);
        u[rt] = MF16(rFl[rt][ki], bh.f, u[rt]);
      }
    }
    #pragma unroll
    for (int rt = 0; rt < 4; ++rt) store_pk<1>(stc, kg, rt, u[rt]);
  }

  // ---- final PR step -> u50; state = z = relu(u50)
  #pragma unroll
  for (int ki = 0; ki < 2; ++ki) {
    FragU bh, bl;
    bh.u = *reinterpret_cast<const uint4*>(stc + 16*ki + 4*kg);
    bl.u = *reinterpret_cast<const uint4*>(stc + 32 + 16*ki + 4*kg);
    #pragma unroll
    for (int rt = 0; rt < 4; ++rt) {
      f32x4 base = (ki == 0) ? c2a[rt] : u[rt];
      u[rt] = MF16(rFh[rt][ki], bh.f, base);
      u[rt] = MF16(rFh[rt][ki], bl.f, u[rt]);
      u[rt] = MF16(rFl[rt][ki], bh.f, u[rt]);
    }
  }
  #pragma unroll
  for (int rt = 0; rt < 4; ++rt) store_pk<2>(stc, kg, rt, u[rt]);

  // ---- zn = relu(W z + bias), C-init = biasC (regs)
  f32x4 zn[4];
  #pragma unroll
  for (int rt = 0; rt < 4; ++rt) zn[rt] = biasC[rt];
  product3(zn, Wss, 1.0f, stc, kg, l15);
  #pragma unroll
  for (int rt = 0; rt < 4; ++rt) store_pk<2>(stc, kg, rt, zn[rt]);   // relu(zn)

  // ---- out = relu(zn) @ Pw^T + Pb via MFMA (A rows 8..15 are zero)
  f32x4 oC = (f32x4){0.f, 0.f, 0.f, 0.f};
  if (kg < 2) {
    const float4 pb = *reinterpret_cast<const float4*>(Pb + 4*kg);
    oC[0] = pb.x; oC[1] = pb.y; oC[2] = pb.z; oC[3] = pb.w;
  }
  #pragma unroll
  for (int ki = 0; ki < 2; ++ki) {
    FragU bh, bl;
    bh.u = *reinterpret_cast<const uint4*>(stc + 16*ki + 4*kg);
    bl.u = *reinterpret_cast<const uint4*>(stc + 32 + 16*ki + 4*kg);
    bf16x8 ah, al;
    build_a16(PwsA, 16, l15, 32*ki + 8*kg, 1.0f, ah, al);
    oC = MF16(ah, bh.f, oC);
    oC = MF16(ah, bl.f, oC);
    oC = MF16(al, bh.f, oC);
  }
  if (kg < 2) {
    float4* op = reinterpret_cast<float4*>(out + ncol * NOUT + 4*kg);
    *op = make_float4(oC[0], oC[1], oC[2], oC[3]);
  }
}

extern "C" void kernel_launch(void* const* d_in, const int* in_sizes, int n_in,
                              void* d_out, int out_size, void* d_ws, size_t ws_size,
                              hipStream_t stream) {
  const float* x  = (const float*)d_in[0];
  const float* W1 = (const float*)d_in[1];
  const float* b1 = (const float*)d_in[2];
  const float* Uw = (const float*)d_in[3];
  const float* Ub = (const float*)d_in[4];
  const float* Aw = (const float*)d_in[5];
  const float* Bw = (const float*)d_in[6];
  const float* Pw = (const float*)d_in[7];
  const float* Pb = (const float*)d_in[8];
  float* outp = (float*)d_out;
  float* mats = (float*)d_ws;                     // ~86 KB of streamed matrices

  k_prep  <<<35, 512, 0, stream>>>(W1, Uw, Aw, Bw, Pw, mats);
  k_solve <<<BROWS/64, 256, 0, stream>>>(x, b1, Ub, Pb, mats, outp);
}

// Round 10
// 124.032 us; speedup vs baseline: 2.4899x; 1.2419x over previous
//
#include <hip/hip_runtime.h>

#define BROWS 131072
#define DD 64
#define INF 128
#define NOUT 8
#define NITER 50
#define STW 76    // state column stride in u32 words
#define GJP 65    // padded f32 stride for the in-place GJ matrix
#define NCHEAP 38 // hi-only iterations (u2..u39)
#define NFULL 9   // full two-plane iterations after the bridge (u41..u49)

// packed fragment tables in ws (u32 words). Layout per table:
// idx = ((ki*4 + rt)*64 + lane)*4 + p   (Pw: (ki*64+lane)*4+p)
#define PK_RH   0        // 2048
#define PK_RL   2048
#define PK_W1H  4096     // 4096 (ki=0..3)
#define PK_W1L  8192
#define PK_UWH  12288    // 2048
#define PK_UWL  14336
#define PK_WSH  16384    // 2048
#define PK_WSL  18432
#define PK_PWH  20480    // 512
#define PK_PWL  20992    // total 21504 words = 86 KB

typedef __attribute__((ext_vector_type(8))) short bf16x8;  // 4 VGPR A/B frag
typedef __attribute__((ext_vector_type(4))) float f32x4;   // 16x16 C/D frag

union FragU { uint4 u; bf16x8 f; };

// pack two f32 into one dword of 2 bf16 (bit-truncation; first arg -> low16)
__device__ __forceinline__ unsigned pk2(float a, float b) {
  return (__float_as_uint(a) >> 16) | (__float_as_uint(b) & 0xFFFF0000u);
}
// exact residual v - bf16trunc(v)
__device__ __forceinline__ float res_lo(float v) {
  return v - __uint_as_float(__float_as_uint(v) & 0xFFFF0000u);
}
// RNE packed convert (T12-proven syntax); convention: S0 -> low16
__device__ __forceinline__ unsigned cvtpk(float a, float b) {
  unsigned w; asm("v_cvt_pk_bf16_f32 %0, %1, %2" : "=v"(w) : "v"(a), "v"(b)); return w;
}
__device__ __forceinline__ f32x4 MF16(bf16x8 a, bf16x8 b, f32x4 c) {
  return __builtin_amdgcn_mfma_f32_16x16x32_bf16(a, b, c, 0, 0, 0);
}

// B-fragment (hi,lo) from 8 explicit f32 values (x rows), truncation split.
__device__ __forceinline__ void build_b8(const float* v, bf16x8& fh, bf16x8& fl) {
  FragU h, l;
  h.u.x = pk2(v[0],v[1]); h.u.y = pk2(v[2],v[3]);
  h.u.z = pk2(v[4],v[5]); h.u.w = pk2(v[6],v[7]);
  l.u.x = pk2(res_lo(v[0]),res_lo(v[1])); l.u.y = pk2(res_lo(v[2]),res_lo(v[3]));
  l.u.z = pk2(res_lo(v[4]),res_lo(v[5])); l.u.w = pk2(res_lo(v[6]),res_lo(v[7]));
  fh = h.f; fl = l.f;
}

// Full two-plane truncation store (proven path). MODE: 0 raw, 1 abs, 2 relu.
template<int MODE>
__device__ __forceinline__ void store_pk(unsigned* stc, int kg, int rt, f32x4 a) {
  float x0 = a[0], x1 = a[1], x2 = a[2], x3 = a[3];
  if (MODE == 1) { x0=fabsf(x0); x1=fabsf(x1); x2=fabsf(x2); x3=fabsf(x3); }
  if (MODE == 2) { x0=fmaxf(x0,0.f); x1=fmaxf(x1,0.f); x2=fmaxf(x2,0.f); x3=fmaxf(x3,0.f); }
  uint2 h, l;
  h.x = pk2(x0, x1);                    h.y = pk2(x2, x3);
  l.x = pk2(res_lo(x0), res_lo(x1));    l.y = pk2(res_lo(x2), res_lo(x3));
  *reinterpret_cast<uint2*>(stc + 8*rt + 2*kg)      = h;
  *reinterpret_cast<uint2*>(stc + 32 + 8*rt + 2*kg) = l;
}

// Cheap-phase store: cvt_pk RNE + packed-bf16 abs (sign-clear), hi plane only.
__device__ __forceinline__ void store_hi_abs(unsigned* stc, int kg, int rt, f32x4 a) {
  uint2 h;
  h.x = cvtpk(a[0], a[1]) & 0x7fff7fffu;
  h.y = cvtpk(a[2], a[3]) & 0x7fff7fffu;
  *reinterpret_cast<uint2*>(stc + 8*rt + 2*kg) = h;
}

// acc[rt] += A @ state, 3-term, A from packed tables (uint4 loads).
__device__ __forceinline__ void product3pk(f32x4* acc, const unsigned* TH,
    const unsigned* TL, const unsigned* stc, int kg, int lane) {
  #pragma unroll
  for (int ki = 0; ki < 2; ++ki) {
    FragU bh, bl;
    bh.u = *reinterpret_cast<const uint4*>(stc + 16*ki + 4*kg);
    bl.u = *reinterpret_cast<const uint4*>(stc + 32 + 16*ki + 4*kg);
    #pragma unroll
    for (int rt = 0; rt < 4; ++rt) {
      FragU ah, al;
      ah.u = *reinterpret_cast<const uint4*>(TH + ((ki*4+rt)*64 + lane)*4);
      al.u = *reinterpret_cast<const uint4*>(TL + ((ki*4+rt)*64 + lane)*4);
      acc[rt] = MF16(ah.f, bh.f, acc[rt]);
      acc[rt] = MF16(ah.f, bl.f, acc[rt]);
      acc[rt] = MF16(al.f, bh.f, acc[rt]);
    }
  }
}

// ---------------------------------------------------------------------------
// Prep, 14 blocks x 512:
//  blocks 0..7 : pack W1 fragments     (8192 word-pairs -> 4096 each plane... e in [0,4096))
//  blocks 8..11: pack Uw fragments     (e in [0,2048))
//  block 12    : pack Pw fragments     (e in [0,512))
//  block 13    : W (f32) + M = 2I - W, in-place f32 GJ, pack Wss + R frags.
// ---------------------------------------------------------------------------
__global__ __launch_bounds__(512) void k_prep(
    const float* __restrict__ W1, const float* __restrict__ Uw,
    const float* __restrict__ Aw, const float* __restrict__ Bw,
    const float* __restrict__ Pw, unsigned* __restrict__ pk) {
  const int b = blockIdx.x, tid = threadIdx.x;

  if (b < 8) {          // ---- W1 fragments: e indexes a word-pair (hi+lo)
    const int e = b * 512 + tid;            // [0, 4096)
    const int p = e & 3, lane = (e >> 2) & 63, rt = (e >> 8) & 3, ki = e >> 10;
    const int j = 16*rt + (lane & 15);
    const int k = 32*ki + 8*(lane >> 4) + 2*p;
    const float v0 = W1[j*INF + k], v1 = W1[j*INF + k + 1];
    pk[PK_W1H + e] = pk2(v0, v1);
    pk[PK_W1L + e] = pk2(res_lo(v0), res_lo(v1));
    return;
  }
  if (b < 12) {         // ---- Uw fragments
    const int e = (b - 8) * 512 + tid;      // [0, 2048)
    const int p = e & 3, lane = (e >> 2) & 63, rt = (e >> 8) & 3, ki = e >> 10;
    const int j = 16*rt + (lane & 15);
    const int k = 32*ki + 8*(lane >> 4) + 2*p;
    const float v0 = Uw[j*DD + k], v1 = Uw[j*DD + k + 1];
    pk[PK_UWH + e] = pk2(v0, v1);
    pk[PK_UWL + e] = pk2(res_lo(v0), res_lo(v1));
    return;
  }
  if (b == 12) {        // ---- Pw fragments (rows 8..15 zero)
    if (tid < 512) {
      const int e = tid;                    // [0, 512)
      const int p = e & 3, lane = (e >> 2) & 63, ki = e >> 8;
      const int o = lane & 15;
      const int k = 32*ki + 8*(lane >> 4) + 2*p;
      const float v0 = (o < NOUT) ? Pw[o*DD + k]     : 0.0f;
      const float v1 = (o < NOUT) ? Pw[o*DD + k + 1] : 0.0f;
      pk[PK_PWH + e] = pk2(v0, v1);
      pk[PK_PWL + e] = pk2(res_lo(v0), res_lo(v1));
    }
    return;
  }

  // ---- block 13: W, GJ inversion, pack Wss + R
  __shared__ float As[DD * DD];      // 16 KB
  __shared__ float MT[DD * GJP];     // 16.6 KB: MT[k*GJP+t] = M[t][k]
  __shared__ float Wls[DD * GJP];    // 16.6 KB: Wls[k*GJP+t] = W[t][k]
  const int t = tid & 63;
  const int cg = tid >> 6;           // 0..7

  #pragma unroll
  for (int q = 0; q < 8; ++q) As[q * 512 + tid] = Aw[q * 512 + tid];
  __syncthreads();

  {
    float s[8];
    #pragma unroll
    for (int q = 0; q < 8; ++q) s[q] = 0.0f;
    for (int i = 0; i < DD; ++i) {
      const float at = As[i*DD + t];
      const float* ak = As + i*DD + 8*cg;
      #pragma unroll
      for (int q = 0; q < 8; ++q) s[q] = fmaf(at, ak[q], s[q]);
    }
    #pragma unroll
    for (int q = 0; q < 8; ++q) {
      const int k = 8*cg + q;
      const float w = ((t == k) ? 0.9f : 0.0f) - s[q] + Bw[t*DD + k] - Bw[k*DD + t];
      Wls[k*GJP + t] = w;
      MT[k*GJP + t] = ((t == k) ? 2.0f : 0.0f) - w;
    }
  }
  __syncthreads();

  #pragma unroll 1
  for (int c = 0; c < DD; ++c) {
    const float praw = MT[c*GJP + c];
    const float f    = MT[c*GJP + t];
    const float p    = 1.0f / praw;
    __syncthreads();
    if (tid < DD) {
      const int j = tid;
      const float v = MT[j*GJP + c];
      MT[j*GJP + c] = (j == c) ? p : v * p;
    }
    __syncthreads();
    if (t != c) {
      #pragma unroll
      for (int jj = 0; jj < 8; ++jj) {
        const int j = 8*cg + jj;
        const float mc  = MT[j*GJP + c];
        const float cur = MT[j*GJP + t];
        MT[j*GJP + t] = fmaf(-f, mc, (j == c) ? 0.0f : cur);
      }
    }
    __syncthreads();
  }
  // MT[a*GJP+b] = Minv[b][a]

  // pack Wss and R fragments (4 word-pairs each per thread)
  #pragma unroll
  for (int e = 0; e < 2048; e += 512) {
    const int ee = e + tid;
    const int p = ee & 3, lane = (ee >> 2) & 63, rt = (ee >> 8) & 3, ki = ee >> 10;
    const int j = 16*rt + (lane & 15);
    const int k = 32*ki + 8*(lane >> 4) + 2*p;
    {  // Wss: Mat[j][k] = Wls[k*GJP + j]
      const float v0 = Wls[k*GJP + j], v1 = Wls[(k+1)*GJP + j];
      pk[PK_WSH + ee] = pk2(v0, v1);
      pk[PK_WSL + ee] = pk2(res_lo(v0), res_lo(v1));
    }
    {  // R: 2*Minv[j][k] - delta = 2*MT[k*GJP+j] - delta
      const float v0 = 2.0f*MT[k*GJP + j]     - ((k   == j) ? 1.0f : 0.0f);
      const float v1 = 2.0f*MT[(k+1)*GJP + j] - ((k+1 == j) ? 1.0f : 0.0f);
      pk[PK_RH + ee] = pk2(v0, v1);
      pk[PK_RL + ee] = pk2(res_lo(v0), res_lo(v1));
    }
  }
}

// ---------------------------------------------------------------------------
// Fused solve. All A-fragments come prepacked from the table (uint4 loads).
// Cheap phase u2..u39: hi-plane state, Rh only (8 MFMA/iter), cvt_pk store.
// Bridge u40 (2-term, full store), full phase u41..u49 (3-term), final relu.
// ---------------------------------------------------------------------------
__global__ __launch_bounds__(256) void k_solve(
    const float* __restrict__ x,  const float* __restrict__ b1,
    const float* __restrict__ Ub, const float* __restrict__ Pb,
    const unsigned* __restrict__ pk, float* __restrict__ out) {
  __shared__ unsigned stp[DD * STW];   // packed state, one 76-word column per batch col
  const int tid  = threadIdx.x;
  const int lane = tid & 63, wv = tid >> 6;
  const int l15  = lane & 15, kg = lane >> 4;
  const int ccol = wv * 16 + l15;
  const size_t ncol = (size_t)blockIdx.x * 64 + ccol;
  unsigned* stc = stp + ccol * STW;

  // R fragments resident in registers for all iterations (uint4 table loads)
  FragU rFh[4][2], rFl[4][2];
  #pragma unroll
  for (int rt = 0; rt < 4; ++rt)
    #pragma unroll
    for (int ki = 0; ki < 2; ++ki) {
      rFh[rt][ki].u = *reinterpret_cast<const uint4*>(pk + PK_RH + ((ki*4+rt)*64 + lane)*4);
      rFl[rt][ki].u = *reinterpret_cast<const uint4*>(pk + PK_RL + ((ki*4+rt)*64 + lane)*4);
    }

  // ---- h = relu(W1 x^T + b1): B from x, A from packed W1 table
  f32x4 hC[4];
  #pragma unroll
  for (int rt = 0; rt < 4; ++rt)
    hC[rt] = *reinterpret_cast<const f32x4*>(b1 + 16*rt + 4*kg);
  #pragma unroll
  for (int ki = 0; ki < 4; ++ki) {                 // K = 128
    const float* xp = x + ncol * INF + 32*ki + 8*kg;
    float bv[8];
    #pragma unroll
    for (int s = 0; s < 8; ++s) bv[s] = xp[s];
    bf16x8 Bh, Bl; build_b8(bv, Bh, Bl);
    #pragma unroll
    for (int rt = 0; rt < 4; ++rt) {
      FragU ah, al;
      ah.u = *reinterpret_cast<const uint4*>(pk + PK_W1H + ((ki*4+rt)*64 + lane)*4);
      al.u = *reinterpret_cast<const uint4*>(pk + PK_W1L + ((ki*4+rt)*64 + lane)*4);
      hC[rt] = MF16(ah.f, Bh, hC[rt]);
      hC[rt] = MF16(ah.f, Bl, hC[rt]);
      hC[rt] = MF16(al.f, Bh, hC[rt]);
    }
  }
  #pragma unroll
  for (int rt = 0; rt < 4; ++rt) store_pk<2>(stc, kg, rt, hC[rt]);   // relu(h), full

  // ---- bias = Uw h + Ub (kept in regs for c2-init and zn C-init)
  f32x4 biasC[4];
  #pragma unroll
  for (int rt = 0; rt < 4; ++rt)
    biasC[rt] = *reinterpret_cast<const f32x4*>(Ub + 16*rt + 4*kg);
  product3pk(biasC, pk + PK_UWH, pk + PK_UWL, stc, kg, lane);
  #pragma unroll
  for (int rt = 0; rt < 4; ++rt) store_pk<0>(stc, kg, rt, biasC[rt]);

  // ---- c2 = R bias + bias (3-term, resident R fragments)
  f32x4 c2a[4];
  #pragma unroll
  for (int rt = 0; rt < 4; ++rt) c2a[rt] = biasC[rt];
  #pragma unroll
  for (int ki = 0; ki < 2; ++ki) {
    FragU bh, bl;
    bh.u = *reinterpret_cast<const uint4*>(stc + 16*ki + 4*kg);
    bl.u = *reinterpret_cast<const uint4*>(stc + 32 + 16*ki + 4*kg);
    #pragma unroll
    for (int rt = 0; rt < 4; ++rt) {
      c2a[rt] = MF16(rFh[rt][ki].f, bh.f, c2a[rt]);
      c2a[rt] = MF16(rFh[rt][ki].f, bl.f, c2a[rt]);
      c2a[rt] = MF16(rFl[rt][ki].f, bh.f, c2a[rt]);
    }
  }
  #pragma unroll
  for (int rt = 0; rt < 4; ++rt) store_hi_abs(stc, kg, rt, c2a[rt]);  // |u1|

  f32x4 u[4];
  // ---- cheap phase: 38 iterations, Rh only (8 MFMA), hi-only state
  #pragma unroll 1
  for (int it = 0; it < NCHEAP; ++it) {
    #pragma unroll
    for (int ki = 0; ki < 2; ++ki) {
      FragU bh;
      bh.u = *reinterpret_cast<const uint4*>(stc + 16*ki + 4*kg);
      #pragma unroll
      for (int rt = 0; rt < 4; ++rt) {
        f32x4 base = (ki == 0) ? c2a[rt] : u[rt];
        u[rt] = MF16(rFh[rt][ki].f, bh.f, base);
      }
    }
    #pragma unroll
    for (int rt = 0; rt < 4; ++rt) store_hi_abs(stc, kg, rt, u[rt]);
  }

  // ---- bridge: 2-term read of hi state, FULL store -> u40
  #pragma unroll
  for (int ki = 0; ki < 2; ++ki) {
    FragU bh;
    bh.u = *reinterpret_cast<const uint4*>(stc + 16*ki + 4*kg);
    #pragma unroll
    for (int rt = 0; rt < 4; ++rt) {
      f32x4 base = (ki == 0) ? c2a[rt] : u[rt];
      u[rt] = MF16(rFh[rt][ki].f, bh.f, base);
      u[rt] = MF16(rFl[rt][ki].f, bh.f, u[rt]);
    }
  }
  #pragma unroll
  for (int rt = 0; rt < 4; ++rt) store_pk<1>(stc, kg, rt, u[rt]);

  // ---- full phase: 9 iterations, 3-term, full store -> u41..u49
  #pragma unroll 1
  for (int it = 0; it < NFULL; ++it) {
    #pragma unroll
    for (int ki = 0; ki < 2; ++ki) {
      FragU bh, bl;
      bh.u = *reinterpret_cast<const uint4*>(stc + 16*ki + 4*kg);
      bl.u = *reinterpret_cast<const uint4*>(stc + 32 + 16*ki + 4*kg);
      #pragma unroll
      for (int rt = 0; rt < 4; ++rt) {
        f32x4 base = (ki == 0) ? c2a[rt] : u[rt];
        u[rt] = MF16(rFh[rt][ki].f, bh.f, base);
        u[rt] = MF16(rFh[rt][ki].f, bl.f, u[rt]);
        u[rt] = MF16(rFl[rt][ki].f, bh.f, u[rt]);
      }
    }
    #pragma unroll
    for (int rt = 0; rt < 4; ++rt) store_pk<1>(stc, kg, rt, u[rt]);
  }

  // ---- final PR step -> u50; state = z = relu(u50)
  #pragma unroll
  for (int ki = 0; ki < 2; ++ki) {
    FragU bh, bl;
    bh.u = *reinterpret_cast<const uint4*>(stc + 16*ki + 4*kg);
    bl.u = *reinterpret_cast<const uint4*>(stc + 32 + 16*ki + 4*kg);
    #pragma unroll
    for (int rt = 0; rt < 4; ++rt) {
      f32x4 base = (ki == 0) ? c2a[rt] : u[rt];
      u[rt] = MF16(rFh[rt][ki].f, bh.f, base);
      u[rt] = MF16(rFh[rt][ki].f, bl.f, u[rt]);
      u[rt] = MF16(rFl[rt][ki].f, bh.f, u[rt]);
    }
  }
  #pragma unroll
  for (int rt = 0; rt < 4; ++rt) store_pk<2>(stc, kg, rt, u[rt]);

  // ---- zn = relu(W z + bias), C-init = biasC (regs)
  f32x4 zn[4];
  #pragma unroll
  for (int rt = 0; rt < 4; ++rt) zn[rt] = biasC[rt];
  product3pk(zn, pk + PK_WSH, pk + PK_WSL, stc, kg, lane);
  #pragma unroll
  for (int rt = 0; rt < 4; ++rt) store_pk<2>(stc, kg, rt, zn[rt]);   // relu(zn)

  // ---- out = relu(zn) @ Pw^T + Pb via MFMA (A rows 8..15 are zero)
  f32x4 oC = (f32x4){0.f, 0.f, 0.f, 0.f};
  if (kg < 2) {
    const float4 pb = *reinterpret_cast<const float4*>(Pb + 4*kg);
    oC[0] = pb.x; oC[1] = pb.y; oC[2] = pb.z; oC[3] = pb.w;
  }
  #pragma unroll
  for (int ki = 0; ki < 2; ++ki) {
    FragU bh, bl, ah, al;
    bh.u = *reinterpret_cast<const uint4*>(stc + 16*ki + 4*kg);
    bl.u = *reinterpret_cast<const uint4*>(stc + 32 + 16*ki + 4*kg);
    ah.u = *reinterpret_cast<const uint4*>(pk + PK_PWH + (ki*64 + lane)*4);
    al.u = *reinterpret_cast<const uint4*>(pk + PK_PWL + (ki*64 + lane)*4);
    oC = MF16(ah.f, bh.f, oC);
    oC = MF16(ah.f, bl.f, oC);
    oC = MF16(al.f, bh.f, oC);
  }
  if (kg < 2) {
    float4* op = reinterpret_cast<float4*>(out + ncol * NOUT + 4*kg);
    *op = make_float4(oC[0], oC[1], oC[2], oC[3]);
  }
}

extern "C" void kernel_launch(void* const* d_in, const int* in_sizes, int n_in,
                              void* d_out, int out_size, void* d_ws, size_t ws_size,
                              hipStream_t stream) {
  const float* x  = (const float*)d_in[0];
  const float* W1 = (const float*)d_in[1];
  const float* b1 = (const float*)d_in[2];
  const float* Uw = (const float*)d_in[3];
  const float* Ub = (const float*)d_in[4];
  const float* Aw = (const float*)d_in[5];
  const float* Bw = (const float*)d_in[6];
  const float* Pw = (const float*)d_in[7];
  const float* Pb = (const float*)d_in[8];
  float* outp = (float*)d_out;
  unsigned* pk = (unsigned*)d_ws;                 // 86 KB packed fragment tables

  k_prep  <<<14, 512, 0, stream>>>(W1, Uw, Aw, Bw, Pw, pk);
  k_solve <<<BROWS/64, 256, 0, stream>>>(x, b1, Ub, Pb, pk, outp);
}

// Round 11
// 123.765 us; speedup vs baseline: 2.4953x; 1.0022x over previous
//
#include <hip/hip_runtime.h>

#define BROWS 131072
#define DD 64
#define INF 128
#define NOUT 8
#define NITER 50
#define STW 76    // state column stride in u32 words
#define GJP 65    // padded f32 stride for the in-place GJ matrix
#define NCHEAP 38 // hi-only iterations (u2..u39)
#define NFULL 9   // full two-plane iterations after the bridge (u41..u49)

// packed fragment tables in ws (u32 words). Layout per table:
// idx = ((ki*4 + rt)*64 + lane)*4 + p   (Pw: (ki*64+lane)*4+p)
#define PK_RH   0        // 2048
#define PK_RL   2048
#define PK_W1H  4096     // 4096 (ki=0..3)
#define PK_W1L  8192
#define PK_UWH  12288    // 2048
#define PK_UWL  14336
#define PK_WSH  16384    // 2048
#define PK_WSL  18432
#define PK_PWH  20480    // 512
#define PK_PWL  20992    // total 21504 words = 86 KB

typedef __attribute__((ext_vector_type(8))) short bf16x8;  // 4 VGPR A/B frag
typedef __attribute__((ext_vector_type(4))) float f32x4;   // 16x16 C/D frag

union FragU { uint4 u; bf16x8 f; };

// pack two f32 into one dword of 2 bf16 (bit-truncation; first arg -> low16)
__device__ __forceinline__ unsigned pk2(float a, float b) {
  return (__float_as_uint(a) >> 16) | (__float_as_uint(b) & 0xFFFF0000u);
}
// exact residual v - bf16trunc(v)
__device__ __forceinline__ float res_lo(float v) {
  return v - __uint_as_float(__float_as_uint(v) & 0xFFFF0000u);
}
// RNE packed convert; convention: S0 -> low16 (validated round 10)
__device__ __forceinline__ unsigned cvtpk(float a, float b) {
  unsigned w; asm("v_cvt_pk_bf16_f32 %0, %1, %2" : "=v"(w) : "v"(a), "v"(b)); return w;
}
__device__ __forceinline__ f32x4 MF16(bf16x8 a, bf16x8 b, f32x4 c) {
  return __builtin_amdgcn_mfma_f32_16x16x32_bf16(a, b, c, 0, 0, 0);
}

// B-fragment (hi,lo) from 8 explicit f32 values (x rows), truncation split.
__device__ __forceinline__ void build_b8(const float* v, bf16x8& fh, bf16x8& fl) {
  FragU h, l;
  h.u.x = pk2(v[0],v[1]); h.u.y = pk2(v[2],v[3]);
  h.u.z = pk2(v[4],v[5]); h.u.w = pk2(v[6],v[7]);
  l.u.x = pk2(res_lo(v[0]),res_lo(v[1])); l.u.y = pk2(res_lo(v[2]),res_lo(v[3]));
  l.u.z = pk2(res_lo(v[4]),res_lo(v[5])); l.u.w = pk2(res_lo(v[6]),res_lo(v[7]));
  fh = h.f; fl = l.f;
}

// Full two-plane truncation store (proven path). MODE: 0 raw, 1 abs, 2 relu.
template<int MODE>
__device__ __forceinline__ void store_pk(unsigned* stc, int kg, int rt, f32x4 a) {
  float x0 = a[0], x1 = a[1], x2 = a[2], x3 = a[3];
  if (MODE == 1) { x0=fabsf(x0); x1=fabsf(x1); x2=fabsf(x2); x3=fabsf(x3); }
  if (MODE == 2) { x0=fmaxf(x0,0.f); x1=fmaxf(x1,0.f); x2=fmaxf(x2,0.f); x3=fmaxf(x3,0.f); }
  uint2 h, l;
  h.x = pk2(x0, x1);                    h.y = pk2(x2, x3);
  l.x = pk2(res_lo(x0), res_lo(x1));    l.y = pk2(res_lo(x2), res_lo(x3));
  *reinterpret_cast<uint2*>(stc + 8*rt + 2*kg)      = h;
  *reinterpret_cast<uint2*>(stc + 32 + 8*rt + 2*kg) = l;
}

// Cheap-phase store: cvt_pk RNE + packed-bf16 abs (sign-clear), hi plane only.
__device__ __forceinline__ void store_hi_abs(unsigned* stc, int kg, int rt, f32x4 a) {
  uint2 h;
  h.x = cvtpk(a[0], a[1]) & 0x7fff7fffu;
  h.y = cvtpk(a[2], a[3]) & 0x7fff7fffu;
  *reinterpret_cast<uint2*>(stc + 8*rt + 2*kg) = h;
}

// acc[rt] += A @ state, 3-term, A from packed tables (uint4 loads).
__device__ __forceinline__ void product3pk(f32x4* acc, const unsigned* TH,
    const unsigned* TL, const unsigned* stc, int kg, int lane) {
  #pragma unroll
  for (int ki = 0; ki < 2; ++ki) {
    FragU bh, bl;
    bh.u = *reinterpret_cast<const uint4*>(stc + 16*ki + 4*kg);
    bl.u = *reinterpret_cast<const uint4*>(stc + 32 + 16*ki + 4*kg);
    #pragma unroll
    for (int rt = 0; rt < 4; ++rt) {
      FragU ah, al;
      ah.u = *reinterpret_cast<const uint4*>(TH + ((ki*4+rt)*64 + lane)*4);
      al.u = *reinterpret_cast<const uint4*>(TL + ((ki*4+rt)*64 + lane)*4);
      acc[rt] = MF16(ah.f, bh.f, acc[rt]);
      acc[rt] = MF16(ah.f, bl.f, acc[rt]);
      acc[rt] = MF16(al.f, bh.f, acc[rt]);
    }
  }
}

// ---------------------------------------------------------------------------
// Prep (unchanged, measured good): packs all A-side fragment tables; block 13
// does the f32 in-place no-pivot Gauss-Jordan and packs Wss + R fragments.
// ---------------------------------------------------------------------------
__global__ __launch_bounds__(512) void k_prep(
    const float* __restrict__ W1, const float* __restrict__ Uw,
    const float* __restrict__ Aw, const float* __restrict__ Bw,
    const float* __restrict__ Pw, unsigned* __restrict__ pk) {
  const int b = blockIdx.x, tid = threadIdx.x;

  if (b < 8) {          // ---- W1 fragments
    const int e = b * 512 + tid;            // [0, 4096)
    const int p = e & 3, lane = (e >> 2) & 63, rt = (e >> 8) & 3, ki = e >> 10;
    const int j = 16*rt + (lane & 15);
    const int k = 32*ki + 8*(lane >> 4) + 2*p;
    const float v0 = W1[j*INF + k], v1 = W1[j*INF + k + 1];
    pk[PK_W1H + e] = pk2(v0, v1);
    pk[PK_W1L + e] = pk2(res_lo(v0), res_lo(v1));
    return;
  }
  if (b < 12) {         // ---- Uw fragments
    const int e = (b - 8) * 512 + tid;      // [0, 2048)
    const int p = e & 3, lane = (e >> 2) & 63, rt = (e >> 8) & 3, ki = e >> 10;
    const int j = 16*rt + (lane & 15);
    const int k = 32*ki + 8*(lane >> 4) + 2*p;
    const float v0 = Uw[j*DD + k], v1 = Uw[j*DD + k + 1];
    pk[PK_UWH + e] = pk2(v0, v1);
    pk[PK_UWL + e] = pk2(res_lo(v0), res_lo(v1));
    return;
  }
  if (b == 12) {        // ---- Pw fragments (rows 8..15 zero)
    if (tid < 512) {
      const int e = tid;                    // [0, 512)
      const int p = e & 3, lane = (e >> 2) & 63, ki = e >> 8;
      const int o = lane & 15;
      const int k = 32*ki + 8*(lane >> 4) + 2*p;
      const float v0 = (o < NOUT) ? Pw[o*DD + k]     : 0.0f;
      const float v1 = (o < NOUT) ? Pw[o*DD + k + 1] : 0.0f;
      pk[PK_PWH + e] = pk2(v0, v1);
      pk[PK_PWL + e] = pk2(res_lo(v0), res_lo(v1));
    }
    return;
  }

  // ---- block 13: W, GJ inversion, pack Wss + R
  __shared__ float As[DD * DD];      // 16 KB
  __shared__ float MT[DD * GJP];     // 16.6 KB: MT[k*GJP+t] = M[t][k]
  __shared__ float Wls[DD * GJP];    // 16.6 KB: Wls[k*GJP+t] = W[t][k]
  const int t = tid & 63;
  const int cg = tid >> 6;           // 0..7

  #pragma unroll
  for (int q = 0; q < 8; ++q) As[q * 512 + tid] = Aw[q * 512 + tid];
  __syncthreads();

  {
    float s[8];
    #pragma unroll
    for (int q = 0; q < 8; ++q) s[q] = 0.0f;
    for (int i = 0; i < DD; ++i) {
      const float at = As[i*DD + t];
      const float* ak = As + i*DD + 8*cg;
      #pragma unroll
      for (int q = 0; q < 8; ++q) s[q] = fmaf(at, ak[q], s[q]);
    }
    #pragma unroll
    for (int q = 0; q < 8; ++q) {
      const int k = 8*cg + q;
      const float w = ((t == k) ? 0.9f : 0.0f) - s[q] + Bw[t*DD + k] - Bw[k*DD + t];
      Wls[k*GJP + t] = w;
      MT[k*GJP + t] = ((t == k) ? 2.0f : 0.0f) - w;
    }
  }
  __syncthreads();

  #pragma unroll 1
  for (int c = 0; c < DD; ++c) {
    const float praw = MT[c*GJP + c];
    const float f    = MT[c*GJP + t];
    const float p    = 1.0f / praw;
    __syncthreads();
    if (tid < DD) {
      const int j = tid;
      const float v = MT[j*GJP + c];
      MT[j*GJP + c] = (j == c) ? p : v * p;
    }
    __syncthreads();
    if (t != c) {
      #pragma unroll
      for (int jj = 0; jj < 8; ++jj) {
        const int j = 8*cg + jj;
        const float mc  = MT[j*GJP + c];
        const float cur = MT[j*GJP + t];
        MT[j*GJP + t] = fmaf(-f, mc, (j == c) ? 0.0f : cur);
      }
    }
    __syncthreads();
  }
  // MT[a*GJP+b] = Minv[b][a]

  #pragma unroll
  for (int e = 0; e < 2048; e += 512) {
    const int ee = e + tid;
    const int p = ee & 3, lane = (ee >> 2) & 63, rt = (ee >> 8) & 3, ki = ee >> 10;
    const int j = 16*rt + (lane & 15);
    const int k = 32*ki + 8*(lane >> 4) + 2*p;
    {  // Wss: Mat[j][k] = Wls[k*GJP + j]
      const float v0 = Wls[k*GJP + j], v1 = Wls[(k+1)*GJP + j];
      pk[PK_WSH + ee] = pk2(v0, v1);
      pk[PK_WSL + ee] = pk2(res_lo(v0), res_lo(v1));
    }
    {  // R: 2*Minv[j][k] - delta
      const float v0 = 2.0f*MT[k*GJP + j]     - ((k   == j) ? 1.0f : 0.0f);
      const float v1 = 2.0f*MT[(k+1)*GJP + j] - ((k+1 == j) ? 1.0f : 0.0f);
      pk[PK_RH + ee] = pk2(v0, v1);
      pk[PK_RL + ee] = pk2(res_lo(v0), res_lo(v1));
    }
  }
}

// ---------------------------------------------------------------------------
// Fused solve, TWO independent 16-col tiles per wave (ILP-2). A-fragments
// shared; B-states/accumulators doubled. biasC eliminated via
// zn = c2 + W (z - c2/2). Cheap phase u2..u39 hi-plane Rh-only; bridge;
// 9 full iterations; final relu step; MFMA epilogue.
// ---------------------------------------------------------------------------
__global__ __launch_bounds__(256) void k_solve(
    const float* __restrict__ x,  const float* __restrict__ b1,
    const float* __restrict__ Ub, const float* __restrict__ Pb,
    const unsigned* __restrict__ pk, float* __restrict__ out) {
  __shared__ unsigned stp[128 * STW];   // two packed state columns per wave-lane set
  const int tid  = threadIdx.x;
  const int lane = tid & 63, wv = tid >> 6;
  const int l15  = lane & 15, kg = lane >> 4;
  const int cc0 = wv * 32 + l15;        // tile0 block-local col
  const size_t nc0 = (size_t)blockIdx.x * 128 + cc0;
  const size_t nc1 = nc0 + 16;
  unsigned* s0 = stp + cc0 * STW;
  unsigned* s1 = s0 + 16 * STW;

  // R fragments resident in registers, shared by both tiles
  FragU rFh[4][2], rFl[4][2];
  #pragma unroll
  for (int rt = 0; rt < 4; ++rt)
    #pragma unroll
    for (int ki = 0; ki < 2; ++ki) {
      rFh[rt][ki].u = *reinterpret_cast<const uint4*>(pk + PK_RH + ((ki*4+rt)*64 + lane)*4);
      rFl[rt][ki].u = *reinterpret_cast<const uint4*>(pk + PK_RL + ((ki*4+rt)*64 + lane)*4);
    }

  // ---- h = relu(W1 x^T + b1) for both tiles
  f32x4 h0[4], h1[4];
  #pragma unroll
  for (int rt = 0; rt < 4; ++rt) {
    h0[rt] = *reinterpret_cast<const f32x4*>(b1 + 16*rt + 4*kg);
    h1[rt] = h0[rt];
  }
  #pragma unroll
  for (int ki = 0; ki < 4; ++ki) {                 // K = 128
    const float* xp0 = x + nc0 * INF + 32*ki + 8*kg;
    const float* xp1 = x + nc1 * INF + 32*ki + 8*kg;
    float bv0[8], bv1[8];
    #pragma unroll
    for (int s = 0; s < 8; ++s) { bv0[s] = xp0[s]; bv1[s] = xp1[s]; }
    bf16x8 B0h, B0l, B1h, B1l;
    build_b8(bv0, B0h, B0l);
    build_b8(bv1, B1h, B1l);
    #pragma unroll
    for (int rt = 0; rt < 4; ++rt) {
      FragU ah, al;
      ah.u = *reinterpret_cast<const uint4*>(pk + PK_W1H + ((ki*4+rt)*64 + lane)*4);
      al.u = *reinterpret_cast<const uint4*>(pk + PK_W1L + ((ki*4+rt)*64 + lane)*4);
      h0[rt] = MF16(ah.f, B0h, h0[rt]);  h1[rt] = MF16(ah.f, B1h, h1[rt]);
      h0[rt] = MF16(ah.f, B0l, h0[rt]);  h1[rt] = MF16(ah.f, B1l, h1[rt]);
      h0[rt] = MF16(al.f, B0h, h0[rt]);  h1[rt] = MF16(al.f, B1h, h1[rt]);
    }
  }
  #pragma unroll
  for (int rt = 0; rt < 4; ++rt) {
    store_pk<2>(s0, kg, rt, h0[rt]);    // relu(h)
    store_pk<2>(s1, kg, rt, h1[rt]);
  }

  // ---- bias = Uw h + Ub (regs, then packed to state; freed after c2)
  f32x4 c20[4], c21[4];                 // will become c2; holds bias first
  #pragma unroll
  for (int rt = 0; rt < 4; ++rt) {
    c20[rt] = *reinterpret_cast<const f32x4*>(Ub + 16*rt + 4*kg);
    c21[rt] = c20[rt];
  }
  product3pk(c20, pk + PK_UWH, pk + PK_UWL, s0, kg, lane);
  product3pk(c21, pk + PK_UWH, pk + PK_UWL, s1, kg, lane);
  #pragma unroll
  for (int rt = 0; rt < 4; ++rt) {
    store_pk<0>(s0, kg, rt, c20[rt]);   // packed bias
    store_pk<0>(s1, kg, rt, c21[rt]);
  }

  // ---- c2 = R bias + bias (3-term; C-init = bias regs, B = packed bias)
  #pragma unroll
  for (int ki = 0; ki < 2; ++ki) {
    FragU b0h, b0l, b1h, b1l;
    b0h.u = *reinterpret_cast<const uint4*>(s0 + 16*ki + 4*kg);
    b0l.u = *reinterpret_cast<const uint4*>(s0 + 32 + 16*ki + 4*kg);
    b1h.u = *reinterpret_cast<const uint4*>(s1 + 16*ki + 4*kg);
    b1l.u = *reinterpret_cast<const uint4*>(s1 + 32 + 16*ki + 4*kg);
    #pragma unroll
    for (int rt = 0; rt < 4; ++rt) {
      c20[rt] = MF16(rFh[rt][ki].f, b0h.f, c20[rt]);
      c21[rt] = MF16(rFh[rt][ki].f, b1h.f, c21[rt]);
      c20[rt] = MF16(rFh[rt][ki].f, b0l.f, c20[rt]);
      c21[rt] = MF16(rFh[rt][ki].f, b1l.f, c21[rt]);
      c20[rt] = MF16(rFl[rt][ki].f, b0h.f, c20[rt]);
      c21[rt] = MF16(rFl[rt][ki].f, b1h.f, c21[rt]);
    }
  }
  #pragma unroll
  for (int rt = 0; rt < 4; ++rt) {
    store_hi_abs(s0, kg, rt, c20[rt]);  // |u1|
    store_hi_abs(s1, kg, rt, c21[rt]);
  }

  f32x4 u0[4], u1[4];
  // ---- cheap phase: 38 iterations, Rh only (8 MFMA per tile), hi-only state
  #pragma unroll 1
  for (int it = 0; it < NCHEAP; ++it) {
    FragU b00, b01, b10, b11;
    b00.u = *reinterpret_cast<const uint4*>(s0 + 4*kg);
    b10.u = *reinterpret_cast<const uint4*>(s1 + 4*kg);
    b01.u = *reinterpret_cast<const uint4*>(s0 + 16 + 4*kg);
    b11.u = *reinterpret_cast<const uint4*>(s1 + 16 + 4*kg);
    #pragma unroll
    for (int rt = 0; rt < 4; ++rt) {
      u0[rt] = MF16(rFh[rt][0].f, b00.f, c20[rt]);
      u1[rt] = MF16(rFh[rt][0].f, b10.f, c21[rt]);
      u0[rt] = MF16(rFh[rt][1].f, b01.f, u0[rt]);
      u1[rt] = MF16(rFh[rt][1].f, b11.f, u1[rt]);
    }
    #pragma unroll
    for (int rt = 0; rt < 4; ++rt) {
      store_hi_abs(s0, kg, rt, u0[rt]);
      store_hi_abs(s1, kg, rt, u1[rt]);
    }
  }

  // ---- bridge: 2-term read of hi state, FULL store -> u40
  #pragma unroll
  for (int ki = 0; ki < 2; ++ki) {
    FragU b0, b1;
    b0.u = *reinterpret_cast<const uint4*>(s0 + 16*ki + 4*kg);
    b1.u = *reinterpret_cast<const uint4*>(s1 + 16*ki + 4*kg);
    #pragma unroll
    for (int rt = 0; rt < 4; ++rt) {
      f32x4 a0 = (ki == 0) ? c20[rt] : u0[rt];
      f32x4 a1 = (ki == 0) ? c21[rt] : u1[rt];
      u0[rt] = MF16(rFh[rt][ki].f, b0.f, a0);
      u1[rt] = MF16(rFh[rt][ki].f, b1.f, a1);
      u0[rt] = MF16(rFl[rt][ki].f, b0.f, u0[rt]);
      u1[rt] = MF16(rFl[rt][ki].f, b1.f, u1[rt]);
    }
  }
  #pragma unroll
  for (int rt = 0; rt < 4; ++rt) {
    store_pk<1>(s0, kg, rt, u0[rt]);
    store_pk<1>(s1, kg, rt, u1[rt]);
  }

  // ---- full phase: NFULL+1 iterations 3-term (last one stores relu -> z)
  #pragma unroll 1
  for (int it = 0; it <= NFULL; ++it) {
    #pragma unroll
    for (int ki = 0; ki < 2; ++ki) {
      FragU b0h, b0l, b1h, b1l;
      b0h.u = *reinterpret_cast<const uint4*>(s0 + 16*ki + 4*kg);
      b0l.u = *reinterpret_cast<const uint4*>(s0 + 32 + 16*ki + 4*kg);
      b1h.u = *reinterpret_cast<const uint4*>(s1 + 16*ki + 4*kg);
      b1l.u = *reinterpret_cast<const uint4*>(s1 + 32 + 16*ki + 4*kg);
      #pragma unroll
      for (int rt = 0; rt < 4; ++rt) {
        f32x4 a0 = (ki == 0) ? c20[rt] : u0[rt];
        f32x4 a1 = (ki == 0) ? c21[rt] : u1[rt];
        u0[rt] = MF16(rFh[rt][ki].f, b0h.f, a0);
        u1[rt] = MF16(rFh[rt][ki].f, b1h.f, a1);
        u0[rt] = MF16(rFh[rt][ki].f, b0l.f, u0[rt]);
        u1[rt] = MF16(rFh[rt][ki].f, b1l.f, u1[rt]);
        u0[rt] = MF16(rFl[rt][ki].f, b0h.f, u0[rt]);
        u1[rt] = MF16(rFl[rt][ki].f, b1h.f, u1[rt]);
      }
    }
    if (it < NFULL) {
      #pragma unroll
      for (int rt = 0; rt < 4; ++rt) {
        store_pk<1>(s0, kg, rt, u0[rt]);
        store_pk<1>(s1, kg, rt, u1[rt]);
      }
    }
  }

  // ---- epilogue: v = relu(u50) - c2/2 (packed); zn = c2 + W v; state=relu(zn)
  #pragma unroll
  for (int rt = 0; rt < 4; ++rt) {
    f32x4 v0, v1;
    #pragma unroll
    for (int r = 0; r < 4; ++r) {
      v0[r] = fmaxf(u0[rt][r], 0.f) - 0.5f * c20[rt][r];
      v1[r] = fmaxf(u1[rt][r], 0.f) - 0.5f * c21[rt][r];
    }
    store_pk<0>(s0, kg, rt, v0);
    store_pk<0>(s1, kg, rt, v1);
  }
  // zn accumulates into c2 regs (C-init = c2)
  product3pk(c20, pk + PK_WSH, pk + PK_WSL, s0, kg, lane);
  product3pk(c21, pk + PK_WSH, pk + PK_WSL, s1, kg, lane);
  #pragma unroll
  for (int rt = 0; rt < 4; ++rt) {
    store_pk<2>(s0, kg, rt, c20[rt]);   // relu(zn)
    store_pk<2>(s1, kg, rt, c21[rt]);
  }

  // ---- out = relu(zn) @ Pw^T + Pb via MFMA (A rows 8..15 zero)
  f32x4 o0 = (f32x4){0.f,0.f,0.f,0.f}, o1 = o0;
  if (kg < 2) {
    const float4 pb = *reinterpret_cast<const float4*>(Pb + 4*kg);
    o0[0] = pb.x; o0[1] = pb.y; o0[2] = pb.z; o0[3] = pb.w;
    o1 = o0;
  }
  #pragma unroll
  for (int ki = 0; ki < 2; ++ki) {
    FragU b0h, b0l, b1h, b1l, ah, al;
    b0h.u = *reinterpret_cast<const uint4*>(s0 + 16*ki + 4*kg);
    b0l.u = *reinterpret_cast<const uint4*>(s0 + 32 + 16*ki + 4*kg);
    b1h.u = *reinterpret_cast<const uint4*>(s1 + 16*ki + 4*kg);
    b1l.u = *reinterpret_cast<const uint4*>(s1 + 32 + 16*ki + 4*kg);
    ah.u = *reinterpret_cast<const uint4*>(pk + PK_PWH + (ki*64 + lane)*4);
    al.u = *reinterpret_cast<const uint4*>(pk + PK_PWL + (ki*64 + lane)*4);
    o0 = MF16(ah.f, b0h.f, o0);  o1 = MF16(ah.f, b1h.f, o1);
    o0 = MF16(ah.f, b0l.f, o0);  o1 = MF16(ah.f, b1l.f, o1);
    o0 = MF16(al.f, b0h.f, o0);  o1 = MF16(al.f, b1h.f, o1);
  }
  if (kg < 2) {
    float4* op0 = reinterpret_cast<float4*>(out + nc0 * NOUT + 4*kg);
    float4* op1 = reinterpret_cast<float4*>(out + nc1 * NOUT + 4*kg);
    *op0 = make_float4(o0[0], o0[1], o0[2], o0[3]);
    *op1 = make_float4(o1[0], o1[1], o1[2], o1[3]);
  }
}

extern "C" void kernel_launch(void* const* d_in, const int* in_sizes, int n_in,
                              void* d_out, int out_size, void* d_ws, size_t ws_size,
                              hipStream_t stream) {
  const float* x  = (const float*)d_in[0];
  const float* W1 = (const float*)d_in[1];
  const float* b1 = (const float*)d_in[2];
  const float* Uw = (const float*)d_in[3];
  const float* Ub = (const float*)d_in[4];
  const float* Aw = (const float*)d_in[5];
  const float* Bw = (const float*)d_in[6];
  const float* Pw = (const float*)d_in[7];
  const float* Pb = (const float*)d_in[8];
  float* outp = (float*)d_out;
  unsigned* pk = (unsigned*)d_ws;                 // 86 KB packed fragment tables

  k_prep  <<<14, 512, 0, stream>>>(W1, Uw, Aw, Bw, Pw, pk);
  k_solve <<<BROWS/128, 256, 0, stream>>>(x, b1, Ub, Pb, pk, outp);
}